// Round 13
// baseline (1936.567 us; speedup 1.0000x reference)
//
#include <hip/hip_runtime.h>

typedef __bf16 bf16x8 __attribute__((ext_vector_type(8)));
typedef __bf16 bf16x4 __attribute__((ext_vector_type(4)));
typedef float  f32x4  __attribute__((ext_vector_type(4)));
typedef unsigned int u32x4 __attribute__((ext_vector_type(4)));

#define MFMA16(a, b, c) __builtin_amdgcn_mfma_f32_16x16x32_bf16(a, b, c, 0, 0, 0)

__device__ __forceinline__ void gload_lds16(const void* g, void* l) {
  __builtin_amdgcn_global_load_lds(
      (const __attribute__((address_space(1))) void*)g,
      (__attribute__((address_space(3))) void*)l, 16, 0, 0);
}

__device__ __forceinline__ void waitvm(int vm) {
  if (vm == 6)      asm volatile("s_waitcnt vmcnt(6)" ::: "memory");
  else if (vm == 4) asm volatile("s_waitcnt vmcnt(4)" ::: "memory");
  else if (vm == 3) asm volatile("s_waitcnt vmcnt(3)" ::: "memory");
  else              asm volatile("s_waitcnt vmcnt(0)" ::: "memory");
}

__device__ __forceinline__ void cvt8(const float* __restrict__ s, __bf16* __restrict__ d) {
  f32x4 a = *(const f32x4*)s, b = *(const f32x4*)(s + 4);
  bf16x8 v;
  v[0] = (__bf16)a[0]; v[1] = (__bf16)a[1]; v[2] = (__bf16)a[2]; v[3] = (__bf16)a[3];
  v[4] = (__bf16)b[0]; v[5] = (__bf16)b[1]; v[6] = (__bf16)b[2]; v[7] = (__bf16)b[3];
  *(bf16x8*)d = v;
}

// ---------------------------------------------------------------- merged prepack (r9 flat one-shot — best measured)
// chunk regions (8-elem units): [0,3145728) qkv | [..,4194304) out | [..,8388608) w1cat
// [..,12582912) w2cat | [..,16678912) head
__global__ __launch_bounds__(256) void prepack_all(
    const float* __restrict__ qkv_w, const float* __restrict__ out_w,
    const float* __restrict__ a_w1, const float* __restrict__ f_w1,
    const float* __restrict__ a_w2, const float* __restrict__ f_w2,
    const float* __restrict__ head_w,
    __bf16* __restrict__ wq, __bf16* __restrict__ wo,
    __bf16* __restrict__ w1c, __bf16* __restrict__ w2c, __bf16* __restrict__ wh) {
  int i = blockIdx.x * 256 + threadIdx.x;
  if (i < 4194304) {
    if (i < 3145728) cvt8(qkv_w + ((size_t)i << 3), wq + ((size_t)i << 3));
    else {
      int j = i - 3145728;
      cvt8(out_w + ((size_t)j << 3), wo + ((size_t)j << 3));
    }
  } else if (i < 8388608) {
    int j = i - 4194304;
    int l = j >> 19, il = j & 524287;
    int k = (il & 127) * 8;
    int r = il >> 7;
    const float* s = (r < 2048)
        ? a_w1 + (size_t)l * 2097152 + ((size_t)r << 10) + k
        : f_w1 + (size_t)l * 2097152 + ((size_t)(r - 2048) << 10) + k;
    cvt8(s, w1c + ((size_t)j << 3));
  } else if (i < 12582912) {
    int j = i - 8388608;
    int l = j >> 19, il = j & 524287;
    int k = (il & 511) * 8;
    int r = il >> 9;
    const float* s = (k < 2048)
        ? a_w2 + (size_t)l * 2097152 + (size_t)r * 2048 + k
        : f_w2 + (size_t)l * 2097152 + (size_t)r * 2048 + (k - 2048);
    cvt8(s, w2c + ((size_t)j << 3));
  } else if (i < 16678912) {
    int j = i - 12582912;
    cvt8(head_w + ((size_t)j << 3), wh + ((size_t)j << 3));
  }
}

// ---------------------------------------------------------------- per-piece kernels (small-ws fallback)
__global__ __launch_bounds__(256) void cvt_kernel(
    const float* __restrict__ s, __bf16* __restrict__ d, int n8) {
  int i = blockIdx.x * 256 + threadIdx.x;
  if (i >= n8) return;
  cvt8(s + ((size_t)i << 3), d + ((size_t)i << 3));
}

__global__ __launch_bounds__(256) void cat_w1_kernel(
    const float* __restrict__ a, const float* __restrict__ f, __bf16* __restrict__ d) {
  int i = blockIdx.x * 256 + threadIdx.x;
  int k = (i & 127) * 8;
  int r = i >> 7;
  const float* s = (r < 2048) ? a + ((size_t)r << 10) + k
                              : f + ((size_t)(r - 2048) << 10) + k;
  cvt8(s, d + ((size_t)i << 3));
}

__global__ __launch_bounds__(256) void cat_w2_kernel(
    const float* __restrict__ a, const float* __restrict__ f, __bf16* __restrict__ d) {
  int i = blockIdx.x * 256 + threadIdx.x;
  int k = (i & 511) * 8;
  int r = i >> 9;
  const float* s = (k < 2048) ? a + (size_t)r * 2048 + k
                              : f + (size_t)r * 2048 + (k - 2048);
  cvt8(s, d + ((size_t)i << 3));
}

// ---------------------------------------------------------------- embed
__global__ __launch_bounds__(256) void embed_kernel(
    const int* __restrict__ idx, const float* __restrict__ te,
    const float* __restrict__ pe, float* __restrict__ x) {
  int m = blockIdx.x;
  int t = m & 1023;
  int tok = idx[m];
  int c = threadIdx.x * 4;
  f32x4 a = *(const f32x4*)(te + (size_t)tok * 1024 + c);
  f32x4 p = *(const f32x4*)(pe + (size_t)t * 1024 + c);
  *(f32x4*)(x + (size_t)m * 1024 + c) = a + p;
}

// ---------------------------------------------------------------- layernorm -> bf16
__global__ __launch_bounds__(256) void ln_kernel(
    const float* __restrict__ x, const float* __restrict__ g,
    const float* __restrict__ bb, __bf16* __restrict__ out) {
  int row = blockIdx.x, tid = threadIdx.x;
  int wid = tid >> 6, lane = tid & 63;
  f32x4 v = *(const f32x4*)(x + (size_t)row * 1024 + tid * 4);
  float s = v[0] + v[1] + v[2] + v[3];
  #pragma unroll
  for (int off = 32; off >= 1; off >>= 1) s += __shfl_xor(s, off);
  __shared__ float red1[4], red2[4];
  if (lane == 0) red1[wid] = s;
  __syncthreads();
  float mu = (red1[0] + red1[1] + red1[2] + red1[3]) * (1.0f / 1024.0f);
  float d0 = v[0] - mu, d1 = v[1] - mu, d2 = v[2] - mu, d3 = v[3] - mu;
  float q = d0 * d0 + d1 * d1 + d2 * d2 + d3 * d3;
  #pragma unroll
  for (int off = 32; off >= 1; off >>= 1) q += __shfl_xor(q, off);
  if (lane == 0) red2[wid] = q;
  __syncthreads();
  float var = (red2[0] + red2[1] + red2[2] + red2[3]) * (1.0f / 1024.0f);
  float inv = rsqrtf(var + 1e-5f);
  f32x4 gg = *(const f32x4*)(g + tid * 4);
  f32x4 bv = *(const f32x4*)(bb + tid * 4);
  bf16x4 o4;
  o4[0] = (__bf16)(d0 * inv * gg[0] + bv[0]);
  o4[1] = (__bf16)(d1 * inv * gg[1] + bv[1]);
  o4[2] = (__bf16)(d2 * inv * gg[2] + bv[2]);
  o4[3] = (__bf16)(d3 * inv * gg[3] + bv[3]);
  *(bf16x4*)(out + (size_t)row * 1024 + tid * 4) = o4;
}

// ---------------------------------------------------------------- big-tile GEMM: 256x256, BK=32, 512 thr, triple-buffered LDS (r3/r7 proven)
// C[M,N] = A[M,K] @ B[N,K]^T, all bf16 in, EPI: 0 f32, 1 bf16, 2 gelu->bf16
template <int EPI>
__global__ __launch_bounds__(512, 2) void gemm256(
    const __bf16* __restrict__ A, int lda,
    const __bf16* __restrict__ B, int ldb, int K,
    float* __restrict__ Cf, __bf16* __restrict__ Cb, int ldc, int nbx) {
  __shared__ __align__(16) __bf16 lds[49152];  // 3 bufs x (A 8192 + B 8192) elems
  const int tid = threadIdx.x, lane = tid & 63, w = tid >> 6;
  const int l15 = lane & 15, l4 = lane >> 4;
  const int wr = w >> 2, wc = w & 3;

  int nwg = gridDim.x, id = blockIdx.x;
  int q = nwg >> 3, r = nwg & 7;
  int xcd = id & 7, pos = id >> 3;
  int nid = (xcd < r ? xcd * (q + 1) : r * (q + 1) + (xcd - r) * q) + pos;
  int row0 = (nid % nbx) * 256, col0 = (nid / nbx) * 256;

  const __bf16* ag = A + (size_t)row0 * lda;
  const __bf16* bg = B + (size_t)col0 * ldb;

  f32x4 acc[8][4];
  #pragma unroll
  for (int i = 0; i < 8; ++i)
    #pragma unroll
    for (int j = 0; j < 4; ++j) acc[i][j] = (f32x4){0.f, 0.f, 0.f, 0.f};

  int srow[2], scol[2];
  #pragma unroll
  for (int i = 0; i < 2; ++i) {
    int p = (w + i * 8) * 1024 + lane * 16;   // byte within 16 KB half
    int row = p >> 6, ch = (p >> 4) & 3;
    srow[i] = row;
    scol[i] = (ch ^ ((row >> 1) & 3)) * 8;    // pre-swizzled source chunk
  }
  const int fx = (((l4 << 4) ^ (((l15 >> 1) & 3) << 4)) >> 1);  // swizzled frag col (elems)

  auto stageA = [&](int t, int c) {
    #pragma unroll
    for (int i = 0; i < 2; ++i)
      gload_lds16(ag + (size_t)srow[i] * lda + t * 32 + scol[i],
                  &lds[c * 16384 + (w + i * 8) * 512]);
  };
  auto stageB = [&](int t, int c) {
    #pragma unroll
    for (int i = 0; i < 2; ++i)
      gload_lds16(bg + (size_t)srow[i] * ldb + t * 32 + scol[i],
                  &lds[c * 16384 + 8192 + (w + i * 8) * 512]);
  };

  auto kgroup = [&](int t2, int c, int cn, int vm, bool stg) {
    if (stg) stageA(t2, cn);
    waitvm(vm);
    __builtin_amdgcn_sched_barrier(0);
    __builtin_amdgcn_s_barrier();
    __builtin_amdgcn_sched_barrier(0);
    const int cb = c * 16384;
    bf16x8 bfr[4], af[4];
    #pragma unroll
    for (int ni = 0; ni < 4; ++ni)
      bfr[ni] = *(const bf16x8*)&lds[cb + 8192 + (wc * 64 + ni * 16 + l15) * 32 + fx];
    #pragma unroll
    for (int mi = 0; mi < 4; ++mi)
      af[mi] = *(const bf16x8*)&lds[cb + (wr * 128 + mi * 16 + l15) * 32 + fx];
    __builtin_amdgcn_s_setprio(1);
    #pragma unroll
    for (int mi = 0; mi < 4; ++mi)
      #pragma unroll
      for (int ni = 0; ni < 4; ++ni)
        acc[mi][ni] = MFMA16(af[mi], bfr[ni], acc[mi][ni]);
    __builtin_amdgcn_s_setprio(0);
    #pragma unroll
    for (int mi = 0; mi < 4; ++mi)
      af[mi] = *(const bf16x8*)&lds[cb + (wr * 128 + (mi + 4) * 16 + l15) * 32 + fx];
    if (stg) stageB(t2, cn);
    __builtin_amdgcn_s_setprio(1);
    #pragma unroll
    for (int mi = 0; mi < 4; ++mi)
      #pragma unroll
      for (int ni = 0; ni < 4; ++ni)
        acc[mi + 4][ni] = MFMA16(af[mi], bfr[ni], acc[mi + 4][ni]);
    __builtin_amdgcn_s_setprio(0);
    __builtin_amdgcn_sched_barrier(0);
    __builtin_amdgcn_s_barrier();
    __builtin_amdgcn_sched_barrier(0);
  };

  const int NT = K >> 5;
  stageA(0, 0); stageB(0, 0);
  stageA(1, 1); stageB(1, 1);

  int c = 0;
  for (int t = 0; t < NT - 2; ++t) {
    int cn = c + 2; if (cn >= 3) cn -= 3;
    kgroup(t + 2, c, cn, 6, true);
    c = (c == 2) ? 0 : c + 1;
  }
  kgroup(0, c, 0, 4, false);
  c = (c == 2) ? 0 : c + 1;
  kgroup(0, c, 0, 0, false);

  #pragma unroll
  for (int mi = 0; mi < 8; ++mi)
    #pragma unroll
    for (int ni = 0; ni < 4; ++ni)
      #pragma unroll
      for (int rr = 0; rr < 4; ++rr) {
        int row = row0 + wr * 128 + mi * 16 + l4 * 4 + rr;
        int col = col0 + wc * 64 + ni * 16 + l15;
        float v = acc[mi][ni][rr];
        size_t off = (size_t)row * ldc + col;
        if (EPI == 0) {
          Cf[off] = v;
        } else if (EPI == 1) {
          Cb[off] = (__bf16)v;
        } else {
          float gv = 0.5f * v * (1.0f + erff(v * 0.70710678118654752f));
          Cb[off] = (__bf16)gv;
        }
      }
}

// ---------------------------------------------------------------- 128-tile GEMM, 3-buffer 2-ahead counted-vmcnt
// EPI: 0 f32, 1 bf16, 2 gelu->bf16, 3 f32 resid add
template <int BN, int EPI>
__global__ __launch_bounds__(256) void gemm_bf16(
    const __bf16* __restrict__ A, int lda,
    const __bf16* __restrict__ B, int ldb, int K,
    float* __restrict__ Cf, __bf16* __restrict__ Cb, int ldc,
    const float* __restrict__ resid, int nbx) {
  constexpr int ACCN = BN / 32;
  constexpr int LB = BN / 64;
  constexpr int L = 2 + LB;
  __shared__ __align__(16) __bf16 As[3 * 4096];
  __shared__ __align__(16) __bf16 Bs[3 * BN * 32];

  int nwg = gridDim.x, id = blockIdx.x;
  int q = nwg >> 3, r = nwg & 7;
  int xcd = id & 7, pos = id >> 3;
  int nid = (xcd < r ? xcd * (q + 1) : r * (q + 1) + (xcd - r) * q) + pos;
  int row0 = (nid % nbx) * 128;
  int col0 = (nid / nbx) * BN;

  const int tid = threadIdx.x, lane = tid & 63, wid = tid >> 6;
  const int l15 = lane & 15, l4 = lane >> 4;
  const int wr = wid >> 1, wc = wid & 1;
  const int fx = (((l4 << 4) ^ (((l15 >> 1) & 3) << 4)) >> 1);

  f32x4 acc[4][ACCN];
  #pragma unroll
  for (int i = 0; i < 4; ++i)
    #pragma unroll
    for (int j = 0; j < ACCN; ++j) acc[i][j] = (f32x4){0.f, 0.f, 0.f, 0.f};

  const __bf16* aptr = A + (size_t)row0 * lda;
  const __bf16* bptr = B + (size_t)col0 * ldb;

  auto stage = [&](int t, int p) {
    #pragma unroll
    for (int i = 0; i < 2; ++i) {
      int ch = tid + 256 * i;
      int rr = ch >> 2, kc = ch & 3;
      gload_lds16(aptr + (size_t)rr * lda + t * 32 + (kc ^ ((rr >> 1) & 3)) * 8,
                  &As[p * 4096 + ch * 8]);
    }
    #pragma unroll
    for (int i = 0; i < LB; ++i) {
      int ch = tid + 256 * i;
      int rr = ch >> 2, kc = ch & 3;
      gload_lds16(bptr + (size_t)rr * ldb + t * 32 + (kc ^ ((rr >> 1) & 3)) * 8,
                  &Bs[p * BN * 32 + ch * 8]);
    }
  };

  const int NT = K >> 5;
  stage(0, 0);
  stage(1, 1);
  int p = 0;
  for (int t = 0; t < NT; ++t) {
    bool stg = (t + 2 < NT);
    if (stg) {
      int ps = p + 2; if (ps >= 3) ps -= 3;
      stage(t + 2, ps);
    }
    waitvm(stg ? 2 * L : ((t + 1 < NT) ? L : 0));
    __builtin_amdgcn_sched_barrier(0);
    __builtin_amdgcn_s_barrier();
    __builtin_amdgcn_sched_barrier(0);
    bf16x8 af[4], bfr[ACCN];
    #pragma unroll
    for (int mi = 0; mi < 4; ++mi)
      af[mi] = *(const bf16x8*)&As[p * 4096 + (wr * 64 + mi * 16 + l15) * 32 + fx];
    #pragma unroll
    for (int ni = 0; ni < ACCN; ++ni)
      bfr[ni] = *(const bf16x8*)&Bs[p * BN * 32 + (wc * (BN / 2) + ni * 16 + l15) * 32 + fx];
    __builtin_amdgcn_s_setprio(1);
    #pragma unroll
    for (int mi = 0; mi < 4; ++mi)
      #pragma unroll
      for (int ni = 0; ni < ACCN; ++ni)
        acc[mi][ni] = MFMA16(af[mi], bfr[ni], acc[mi][ni]);
    __builtin_amdgcn_s_setprio(0);
    __builtin_amdgcn_sched_barrier(0);
    __builtin_amdgcn_s_barrier();
    __builtin_amdgcn_sched_barrier(0);
    p = (p == 2) ? 0 : p + 1;
  }

  #pragma unroll
  for (int mi = 0; mi < 4; ++mi)
    #pragma unroll
    for (int ni = 0; ni < ACCN; ++ni)
      #pragma unroll
      for (int rr = 0; rr < 4; ++rr) {
        int row = row0 + wr * 64 + mi * 16 + l4 * 4 + rr;
        int col = col0 + wc * (BN / 2) + ni * 16 + l15;
        float v = acc[mi][ni][rr];
        size_t off = (size_t)row * ldc + col;
        if (EPI == 0) {
          Cf[off] = v;
        } else if (EPI == 1) {
          Cb[off] = (__bf16)v;
        } else if (EPI == 2) {
          float gv = 0.5f * v * (1.0f + erff(v * 0.70710678118654752f));
          Cb[off] = (__bf16)gv;
        } else {
          Cf[off] = resid[off] + v;
        }
      }
}

// ---------------------------------------------------------------- sliding-window attention (sync-minimal)
// Q,K fragments direct from global (L2-resident); Ssm wave-private LDS (no barriers);
// only V^T staging is cross-wave shared (2 syncs per tile).
__global__ __launch_bounds__(256) void attn_kernel(
    const __bf16* __restrict__ qkv, __bf16* __restrict__ o) {
  const int bid = blockIdx.x;
  const int qt = bid & 15, h = (bid >> 4) & 15, b = bid >> 8;
  const int qs = qt * 64;
  const int ntiles = (qt + 1 < 5) ? (qt + 1) : 5;
  const int kt0 = qt - (ntiles - 1);

  __shared__ __align__(16) __bf16 Vt[64][72];    // V^T tile (shared)
  __shared__ __align__(16) __bf16 Ssm[64][328];  // scores->probs (wave-private rows)
  __shared__ float rsum[64];

  const int tid = threadIdx.x;
  const int lane = tid & 63, wid = tid >> 6;
  const int l15 = lane & 15, l4 = lane >> 4;
  const size_t rs = 3072;

  // Q fragments direct from global: wave w owns q-rows qs+16w .. qs+16w+15
  const __bf16* qrow =
      qkv + ((size_t)(b * 1024 + qs + 16 * wid + l15)) * rs + h * 64;
  bf16x8 aq[2];
  aq[0] = *(const bf16x8*)(qrow + l4 * 8);
  aq[1] = *(const bf16x8*)(qrow + 32 + l4 * 8);

  // ---- phase 1: scores; K fragments direct from global (no LDS, no syncs)
  for (int it = 0; it < ntiles; ++it) {
    int kt = kt0 + it;
    const __bf16* kbase = qkv + ((size_t)(b * 1024 + kt * 64)) * rs + 1024 + h * 64;
    #pragma unroll
    for (int n = 0; n < 4; ++n) {
      const __bf16* krow = kbase + (size_t)(n * 16 + l15) * rs;
      bf16x8 bk0 = *(const bf16x8*)(krow + l4 * 8);
      bf16x8 bk1 = *(const bf16x8*)(krow + 32 + l4 * 8);
      f32x4 c4 = (f32x4){0.f, 0.f, 0.f, 0.f};
      c4 = MFMA16(aq[0], bk0, c4);
      c4 = MFMA16(aq[1], bk1, c4);
      int kj = kt * 64 + n * 16 + l15;
      int colS = it * 64 + n * 16 + l15;
      #pragma unroll
      for (int rr = 0; rr < 4; ++rr) {
        int qi = qs + 16 * wid + l4 * 4 + rr;
        int d = qi - kj;
        float sv = c4[rr] * 0.125f;
        Ssm[16 * wid + l4 * 4 + rr][colS] =
            (d >= 0 && d < 256) ? (__bf16)sv : (__bf16)(-1e30f);
      }
    }
  }
  // no barrier: Ssm rows are wave-private; wave-lockstep LDS ordering suffices

  // ---- phase 2: softmax, 16-lane group per row, 4 rows per wave per iter
  const int nc = ntiles * 4;
  for (int ro = 0; ro < 4; ++ro) {
    int row = 16 * wid + ro * 4 + l4;
    float vals[20];
    #pragma unroll
    for (int i = 0; i < 20; ++i) vals[i] = -3e38f;
    #pragma unroll
    for (int i = 0; i < 20; ++i)
      if (i < nc) vals[i] = (float)Ssm[row][l15 + 16 * i];
    float m = vals[0];
    #pragma unroll
    for (int i = 1; i < 20; ++i) m = fmaxf(m, vals[i]);
    #pragma unroll
    for (int off = 8; off >= 1; off >>= 1) m = fmaxf(m, __shfl_xor(m, off));
    float s = 0.f;
    #pragma unroll
    for (int i = 0; i < 20; ++i)
      if (i < nc) {
        float pp = __expf(vals[i] - m);
        s += pp;
        Ssm[row][l15 + 16 * i] = (__bf16)pp;
      }
    #pragma unroll
    for (int off = 8; off >= 1; off >>= 1) s += __shfl_xor(s, off);
    if (l15 == 0) rsum[row] = s;
  }

  // ---- phase 3: O = P @ V ; V^T staged in shared LDS (2 syncs per tile)
  f32x4 oacc[4];
  #pragma unroll
  for (int n = 0; n < 4; ++n) oacc[n] = (f32x4){0.f, 0.f, 0.f, 0.f};

  for (int it = 0; it < ntiles; ++it) {
    int kt = kt0 + it;
    const __bf16* vbase = qkv + ((size_t)(b * 1024 + kt * 64)) * rs + 2048 + h * 64;
    __syncthreads();
    {  // all-thread V^T staging: each thread transposes a 4x4 block
      int k0 = (tid >> 4) * 4, d0 = (tid & 15) * 4;
      bf16x4 vr[4];
      #pragma unroll
      for (int rr = 0; rr < 4; ++rr)
        vr[rr] = *(const bf16x4*)(vbase + (size_t)(k0 + rr) * rs + d0);
      #pragma unroll
      for (int j = 0; j < 4; ++j) {
        bf16x4 wv;
        #pragma unroll
        for (int rr = 0; rr < 4; ++rr) wv[rr] = vr[rr][j];
        *(bf16x4*)&Vt[d0 + j][k0] = wv;
      }
    }
    __syncthreads();
    #pragma unroll
    for (int kk = 0; kk < 2; ++kk) {
      bf16x8 ap = *(const bf16x8*)&Ssm[16 * wid + l15][it * 64 + kk * 32 + l4 * 8];
      #pragma unroll
      for (int n = 0; n < 4; ++n) {
        bf16x8 bv = *(const bf16x8*)&Vt[n * 16 + l15][kk * 32 + l4 * 8];
        oacc[n] = MFMA16(ap, bv, oacc[n]);
      }
    }
  }

  #pragma unroll
  for (int n = 0; n < 4; ++n)
    #pragma unroll
    for (int rr = 0; rr < 4; ++rr) {
      int qrow2 = 16 * wid + l4 * 4 + rr;
      float inv = 1.0f / rsum[qrow2];
      size_t m = (size_t)(b * 1024 + qs + qrow2);
      o[m * 1024 + h * 64 + n * 16 + l15] = (__bf16)(oacc[n][rr] * inv);
    }
}

// ---------------------------------------------------------------- launch
extern "C" void kernel_launch(void* const* d_in, const int* in_sizes, int n_in,
                              void* d_out, int out_size, void* d_ws, size_t ws_size,
                              hipStream_t stream) {
  (void)in_sizes; (void)n_in; (void)out_size;
  const int*   idx     = (const int*)d_in[0];
  const float* tok_emb = (const float*)d_in[1];
  const float* pos_emb = (const float*)d_in[2];
  const float* ln1_g   = (const float*)d_in[3];
  const float* ln1_b   = (const float*)d_in[4];
  const float* qkv_w   = (const float*)d_in[5];
  const float* out_w   = (const float*)d_in[6];
  const float* ln2_g   = (const float*)d_in[7];
  const float* ln2_b   = (const float*)d_in[8];
  const float* a_w1    = (const float*)d_in[9];
  const float* a_w2    = (const float*)d_in[10];
  const float* f_w1    = (const float*)d_in[11];
  const float* f_w2    = (const float*)d_in[12];
  const float* lnf_g   = (const float*)d_in[13];
  const float* lnf_b   = (const float*)d_in[14];
  const float* head_w  = (const float*)d_in[15];
  float* out = (float*)d_out;

  char* ws = (char*)d_ws;
  float*  x    = (float*)(ws);                    // 2048x1024 f32
  __bf16* h    = (__bf16*)(ws + 8388608);         // 2048x1024 bf16
  __bf16* qkv  = (__bf16*)(ws + 12582912);        // 2048x3072 bf16
  __bf16* oatt = (__bf16*)(ws + 25165824);        // 2048x1024 bf16
  __bf16* gcat = (__bf16*)(ws + 29360128);        // 2048x4096 bf16

  const bool full = ws_size >= 313000000ull;

  __bf16 *wq, *wo, *w1c, *w2c, *wh;
  if (full) {
    wq  = (__bf16*)(ws + 46137344);   // 8x3072x1024
    wo  = (__bf16*)(ws + 96468992);   // 8x1024x1024
    w1c = (__bf16*)(ws + 113246208);  // 8x4096x1024
    w2c = (__bf16*)(ws + 180355072);  // 8x1024x4096
    wh  = (__bf16*)(ws + 247463936);  // 32000x1024
    prepack_all<<<65152, 256, 0, stream>>>(
        qkv_w, out_w, a_w1, f_w1, a_w2, f_w2, head_w, wq, wo, w1c, w2c, wh);
  } else {
    wq  = (__bf16*)(ws + 46137344);
    wo  = (__bf16*)(ws + 52428800);
    w1c = (__bf16*)(ws + 54525952);
    w2c = (__bf16*)(ws + 62914560);
    wh  = (__bf16*)(ws + 46137344);
  }

  embed_kernel<<<2048, 256, 0, stream>>>(idx, tok_emb, pos_emb, x);

  for (int l = 0; l < 8; ++l) {
    const __bf16 *wq_l, *wo_l, *w1_l, *w2_l;
    if (full) {
      wq_l = wq + (size_t)l * 3072 * 1024;
      wo_l = wo + (size_t)l * 1024 * 1024;
      w1_l = w1c + (size_t)l * 4096 * 1024;
      w2_l = w2c + (size_t)l * 1024 * 4096;
    } else {
      cvt_kernel<<<1536, 256, 0, stream>>>(qkv_w + (size_t)l * 3072 * 1024, wq, 393216);
      cvt_kernel<<<512, 256, 0, stream>>>(out_w + (size_t)l * 1024 * 1024, wo, 131072);
      cat_w1_kernel<<<2048, 256, 0, stream>>>(
          a_w1 + (size_t)l * 2048 * 1024, f_w1 + (size_t)l * 2048 * 1024, w1c);
      cat_w2_kernel<<<2048, 256, 0, stream>>>(
          a_w2 + (size_t)l * 1024 * 2048, f_w2 + (size_t)l * 1024 * 2048, w2c);
      wq_l = wq; wo_l = wo; w1_l = w1c; w2_l = w2c;
    }

    ln_kernel<<<2048, 256, 0, stream>>>(x, ln1_g + l * 1024, ln1_b + l * 1024, h);
    gemm_bf16<128, 1><<<16 * 24, 256, 0, stream>>>(
        h, 1024, wq_l, 1024, 1024, nullptr, qkv, 3072, nullptr, 16);
    attn_kernel<<<512, 256, 0, stream>>>(qkv, oatt);
    gemm_bf16<64, 3><<<16 * 16, 256, 0, stream>>>(
        oatt, 1024, wo_l, 1024, 1024, x, nullptr, 1024, x, 16);
    ln_kernel<<<2048, 256, 0, stream>>>(x, ln2_g + l * 1024, ln2_b + l * 1024, h);
    gemm_bf16<128, 2><<<16 * 32, 256, 0, stream>>>(
        h, 1024, w1_l, 1024, 1024, nullptr, gcat, 4096, nullptr, 16);
    gemm_bf16<64, 3><<<16 * 16, 256, 0, stream>>>(
        gcat, 4096, w2_l, 4096, 4096, x, nullptr, 1024, x, 16);
  }

  if (!full) {
    cvt_kernel<<<16000, 256, 0, stream>>>(head_w, wh, 4096000);
  }
  ln_kernel<<<2048, 256, 0, stream>>>(x, lnf_g, lnf_b, h);
  gemm256<0><<<8 * 125, 512, 0, stream>>>(
      h, 1024, wh, 1024, 1024, out, nullptr, 32000, 8);
}

// Round 14
// 1936.399 us; speedup vs baseline: 1.0001x; 1.0001x over previous
//
#include <hip/hip_runtime.h>

typedef __bf16 bf16x8 __attribute__((ext_vector_type(8)));
typedef __bf16 bf16x4 __attribute__((ext_vector_type(4)));
typedef float  f32x4  __attribute__((ext_vector_type(4)));
typedef unsigned int u32x4 __attribute__((ext_vector_type(4)));

#define MFMA16(a, b, c) __builtin_amdgcn_mfma_f32_16x16x32_bf16(a, b, c, 0, 0, 0)

__device__ __forceinline__ void gload_lds16(const void* g, void* l) {
  __builtin_amdgcn_global_load_lds(
      (const __attribute__((address_space(1))) void*)g,
      (__attribute__((address_space(3))) void*)l, 16, 0, 0);
}

__device__ __forceinline__ void waitvm(int vm) {
  if (vm == 6)      asm volatile("s_waitcnt vmcnt(6)" ::: "memory");
  else if (vm == 5) asm volatile("s_waitcnt vmcnt(5)" ::: "memory");
  else if (vm == 4) asm volatile("s_waitcnt vmcnt(4)" ::: "memory");
  else if (vm == 3) asm volatile("s_waitcnt vmcnt(3)" ::: "memory");
  else if (vm == 2) asm volatile("s_waitcnt vmcnt(2)" ::: "memory");
  else              asm volatile("s_waitcnt vmcnt(0)" ::: "memory");
}

__device__ __forceinline__ void cvt8(const float* __restrict__ s, __bf16* __restrict__ d) {
  f32x4 a = *(const f32x4*)s, b = *(const f32x4*)(s + 4);
  bf16x8 v;
  v[0] = (__bf16)a[0]; v[1] = (__bf16)a[1]; v[2] = (__bf16)a[2]; v[3] = (__bf16)a[3];
  v[4] = (__bf16)b[0]; v[5] = (__bf16)b[1]; v[6] = (__bf16)b[2]; v[7] = (__bf16)b[3];
  *(bf16x8*)d = v;
}

// ---------------------------------------------------------------- merged prepack (flat one-shot — best measured ~165us)
__global__ __launch_bounds__(256) void prepack_all(
    const float* __restrict__ qkv_w, const float* __restrict__ out_w,
    const float* __restrict__ a_w1, const float* __restrict__ f_w1,
    const float* __restrict__ a_w2, const float* __restrict__ f_w2,
    const float* __restrict__ head_w,
    __bf16* __restrict__ wq, __bf16* __restrict__ wo,
    __bf16* __restrict__ w1c, __bf16* __restrict__ w2c, __bf16* __restrict__ wh) {
  int i = blockIdx.x * 256 + threadIdx.x;
  if (i < 4194304) {
    if (i < 3145728) cvt8(qkv_w + ((size_t)i << 3), wq + ((size_t)i << 3));
    else {
      int j = i - 3145728;
      cvt8(out_w + ((size_t)j << 3), wo + ((size_t)j << 3));
    }
  } else if (i < 8388608) {
    int j = i - 4194304;
    int l = j >> 19, il = j & 524287;
    int k = (il & 127) * 8;
    int r = il >> 7;
    const float* s = (r < 2048)
        ? a_w1 + (size_t)l * 2097152 + ((size_t)r << 10) + k
        : f_w1 + (size_t)l * 2097152 + ((size_t)(r - 2048) << 10) + k;
    cvt8(s, w1c + ((size_t)j << 3));
  } else if (i < 12582912) {
    int j = i - 8388608;
    int l = j >> 19, il = j & 524287;
    int k = (il & 511) * 8;
    int r = il >> 9;
    const float* s = (k < 2048)
        ? a_w2 + (size_t)l * 2097152 + (size_t)r * 2048 + k
        : f_w2 + (size_t)l * 2097152 + (size_t)r * 2048 + (k - 2048);
    cvt8(s, w2c + ((size_t)j << 3));
  } else if (i < 16678912) {
    int j = i - 12582912;
    cvt8(head_w + ((size_t)j << 3), wh + ((size_t)j << 3));
  }
}

// ---------------------------------------------------------------- per-piece kernels (small-ws fallback)
__global__ __launch_bounds__(256) void cvt_kernel(
    const float* __restrict__ s, __bf16* __restrict__ d, int n8) {
  int i = blockIdx.x * 256 + threadIdx.x;
  if (i >= n8) return;
  cvt8(s + ((size_t)i << 3), d + ((size_t)i << 3));
}

__global__ __launch_bounds__(256) void cat_w1_kernel(
    const float* __restrict__ a, const float* __restrict__ f, __bf16* __restrict__ d) {
  int i = blockIdx.x * 256 + threadIdx.x;
  int k = (i & 127) * 8;
  int r = i >> 7;
  const float* s = (r < 2048) ? a + ((size_t)r << 10) + k
                              : f + ((size_t)(r - 2048) << 10) + k;
  cvt8(s, d + ((size_t)i << 3));
}

__global__ __launch_bounds__(256) void cat_w2_kernel(
    const float* __restrict__ a, const float* __restrict__ f, __bf16* __restrict__ d) {
  int i = blockIdx.x * 256 + threadIdx.x;
  int k = (i & 511) * 8;
  int r = i >> 9;
  const float* s = (k < 2048) ? a + (size_t)r * 2048 + k
                              : f + (size_t)r * 2048 + (k - 2048);
  cvt8(s, d + ((size_t)i << 3));
}

// ---------------------------------------------------------------- embed
__global__ __launch_bounds__(256) void embed_kernel(
    const int* __restrict__ idx, const float* __restrict__ te,
    const float* __restrict__ pe, float* __restrict__ x) {
  int m = blockIdx.x;
  int t = m & 1023;
  int tok = idx[m];
  int c = threadIdx.x * 4;
  f32x4 a = *(const f32x4*)(te + (size_t)tok * 1024 + c);
  f32x4 p = *(const f32x4*)(pe + (size_t)t * 1024 + c);
  *(f32x4*)(x + (size_t)m * 1024 + c) = a + p;
}

// ---------------------------------------------------------------- layernorm -> bf16
__global__ __launch_bounds__(256) void ln_kernel(
    const float* __restrict__ x, const float* __restrict__ g,
    const float* __restrict__ bb, __bf16* __restrict__ out) {
  int row = blockIdx.x, tid = threadIdx.x;
  int wid = tid >> 6, lane = tid & 63;
  f32x4 v = *(const f32x4*)(x + (size_t)row * 1024 + tid * 4);
  float s = v[0] + v[1] + v[2] + v[3];
  #pragma unroll
  for (int off = 32; off >= 1; off >>= 1) s += __shfl_xor(s, off);
  __shared__ float red1[4], red2[4];
  if (lane == 0) red1[wid] = s;
  __syncthreads();
  float mu = (red1[0] + red1[1] + red1[2] + red1[3]) * (1.0f / 1024.0f);
  float d0 = v[0] - mu, d1 = v[1] - mu, d2 = v[2] - mu, d3 = v[3] - mu;
  float q = d0 * d0 + d1 * d1 + d2 * d2 + d3 * d3;
  #pragma unroll
  for (int off = 32; off >= 1; off >>= 1) q += __shfl_xor(q, off);
  if (lane == 0) red2[wid] = q;
  __syncthreads();
  float var = (red2[0] + red2[1] + red2[2] + red2[3]) * (1.0f / 1024.0f);
  float inv = rsqrtf(var + 1e-5f);
  f32x4 gg = *(const f32x4*)(g + tid * 4);
  f32x4 bv = *(const f32x4*)(bb + tid * 4);
  bf16x4 o4;
  o4[0] = (__bf16)(d0 * inv * gg[0] + bv[0]);
  o4[1] = (__bf16)(d1 * inv * gg[1] + bv[1]);
  o4[2] = (__bf16)(d2 * inv * gg[2] + bv[2]);
  o4[3] = (__bf16)(d3 * inv * gg[3] + bv[3]);
  *(bf16x4*)(out + (size_t)row * 1024 + tid * 4) = o4;
}

// ---------------------------------------------------------------- big-tile GEMM: 256x256, BK=32, 512 thr, 3-buffer LDS,
// 4-phase deep-prefetch: 1 half-tile staged per phase, tile t+2 spread over tile t's
// phases (>=4 phases latency cover per half), single counted vmcnt(5) per tile,
// 2 barriers per tile. C[M,N] = A[M,K] @ B[N,K]^T. EPI: 0 f32, 1 bf16, 2 gelu->bf16
template <int EPI>
__global__ __launch_bounds__(512, 2) void gemm256(
    const __bf16* __restrict__ A, int lda,
    const __bf16* __restrict__ B, int ldb, int K,
    float* __restrict__ Cf, __bf16* __restrict__ Cb, int ldc, int nbx) {
  __shared__ __align__(16) __bf16 lds[49152];  // 3 bufs x (A 8192 + B 8192) elems
  const int tid = threadIdx.x, lane = tid & 63, w = tid >> 6;
  const int l15 = lane & 15, l4 = lane >> 4;
  const int wr = w >> 2, wc = w & 3;

  int nwg = gridDim.x, id = blockIdx.x;
  int q = nwg >> 3, r = nwg & 7;
  int xcd = id & 7, pos = id >> 3;
  int nid = (xcd < r ? xcd * (q + 1) : r * (q + 1) + (xcd - r) * q) + pos;
  int row0 = (nid % nbx) * 256, col0 = (nid / nbx) * 256;

  const __bf16* ag = A + (size_t)row0 * lda;
  const __bf16* bg = B + (size_t)col0 * ldb;

  f32x4 acc[8][4];
  #pragma unroll
  for (int i = 0; i < 8; ++i)
    #pragma unroll
    for (int j = 0; j < 4; ++j) acc[i][j] = (f32x4){0.f, 0.f, 0.f, 0.f};

  // per-thread staging constants for one 8KB half-tile (128 rows x 32 cols)
  const int srow = tid >> 2;
  const int sch = tid & 3;
  const int scol = (sch ^ ((srow >> 1) & 3)) * 8;  // pre-swizzled source chunk
  const int fx = (((l4 << 4) ^ (((l15 >> 1) & 3) << 4)) >> 1);  // swizzled frag col

  // hf: 0 = A rows 0-127, 1 = A rows 128-255, 2 = B rows 0-127, 3 = B rows 128-255
  auto stageHalf = [&](int t, int hf, int b) {
    const __bf16* src = (hf < 2) ? ag : bg;
    const int ld = (hf < 2) ? lda : ldb;
    gload_lds16(src + (size_t)((hf & 1) * 128 + srow) * ld + t * 32 + scol,
                &lds[b * 16384 + (hf >> 1) * 8192 + (hf & 1) * 4096 + tid * 8]);
  };
  auto ldA = [&](int b, int mi) -> bf16x8 {
    return *(const bf16x8*)&lds[b * 16384 + (wr * 128 + mi * 16 + l15) * 32 + fx];
  };
  auto ldB = [&](int b, int ni) -> bf16x8 {
    return *(const bf16x8*)&lds[b * 16384 + 8192 + (wc * 64 + ni * 16 + l15) * 32 + fx];
  };
  auto bar = [&]() {
    __builtin_amdgcn_sched_barrier(0);
    __builtin_amdgcn_s_barrier();
    __builtin_amdgcn_sched_barrier(0);
  };

  const int NT = K >> 5;
  // prologue: tiles 0 and 1 into buffers 0 and 1 (4 halves each)
  #pragma unroll
  for (int hf = 0; hf < 4; ++hf) stageHalf(0, hf, 0);
  #pragma unroll
  for (int hf = 0; hf < 4; ++hf) stageHalf(1, hf, 1);

  bf16x8 af[4], bfr[4];
  int b = 0, bs = 2;
  for (int t = 0; t < NT; ++t) {
    const bool stg = (t + 2 < NT);
    // ---- P0: quadrant (mi 0-3, ni 0-1)
    if (stg) stageHalf(t + 2, 0, bs);
    // in-flight before wait: 4 halves(t) + 4 halves(t+1) + 1 just-issued = 9
    waitvm(stg ? 5 : ((t + 1 < NT) ? 4 : 0));  // drains tile t's 4 halves
    bar();
    #pragma unroll
    for (int mi = 0; mi < 4; ++mi) af[mi] = ldA(b, mi);
    #pragma unroll
    for (int ni = 0; ni < 2; ++ni) bfr[ni] = ldB(b, ni);
    __builtin_amdgcn_s_setprio(1);
    #pragma unroll
    for (int mi = 0; mi < 4; ++mi)
      #pragma unroll
      for (int ni = 0; ni < 2; ++ni)
        acc[mi][ni] = MFMA16(af[mi], bfr[ni], acc[mi][ni]);
    __builtin_amdgcn_s_setprio(0);
    // ---- P1: quadrant (mi 0-3, ni 2-3)
    if (stg) stageHalf(t + 2, 2, bs);
    #pragma unroll
    for (int ni = 2; ni < 4; ++ni) bfr[ni] = ldB(b, ni);
    __builtin_amdgcn_s_setprio(1);
    #pragma unroll
    for (int mi = 0; mi < 4; ++mi)
      #pragma unroll
      for (int ni = 2; ni < 4; ++ni)
        acc[mi][ni] = MFMA16(af[mi], bfr[ni], acc[mi][ni]);
    __builtin_amdgcn_s_setprio(0);
    // ---- P2: quadrant (mi 4-7, ni 2-3)
    if (stg) stageHalf(t + 2, 3, bs);
    #pragma unroll
    for (int mi = 0; mi < 4; ++mi) af[mi] = ldA(b, mi + 4);
    __builtin_amdgcn_s_setprio(1);
    #pragma unroll
    for (int mi = 0; mi < 4; ++mi)
      #pragma unroll
      for (int ni = 2; ni < 4; ++ni)
        acc[mi + 4][ni] = MFMA16(af[mi], bfr[ni], acc[mi + 4][ni]);
    __builtin_amdgcn_s_setprio(0);
    // ---- P3: quadrant (mi 4-7, ni 0-1), operand reuse only
    if (stg) stageHalf(t + 2, 1, bs);
    __builtin_amdgcn_s_setprio(1);
    #pragma unroll
    for (int mi = 0; mi < 4; ++mi)
      #pragma unroll
      for (int ni = 0; ni < 2; ++ni)
        acc[mi + 4][ni] = MFMA16(af[mi], bfr[ni], acc[mi + 4][ni]);
    __builtin_amdgcn_s_setprio(0);
    bar();  // buffer-reuse guard: all reads of tile t done before t+2 staging lands
    b = (b == 2) ? 0 : b + 1;
    bs = (bs == 2) ? 0 : bs + 1;
  }

  #pragma unroll
  for (int mi = 0; mi < 8; ++mi)
    #pragma unroll
    for (int ni = 0; ni < 4; ++ni)
      #pragma unroll
      for (int rr = 0; rr < 4; ++rr) {
        int row = row0 + wr * 128 + mi * 16 + l4 * 4 + rr;
        int col = col0 + wc * 64 + ni * 16 + l15;
        float v = acc[mi][ni][rr];
        size_t off = (size_t)row * ldc + col;
        if (EPI == 0) {
          Cf[off] = v;
        } else if (EPI == 1) {
          Cb[off] = (__bf16)v;
        } else {
          float gv = 0.5f * v * (1.0f + erff(v * 0.70710678118654752f));
          Cb[off] = (__bf16)gv;
        }
      }
}

// ---------------------------------------------------------------- 128-tile GEMM, 3-buffer 2-ahead counted-vmcnt
// EPI: 0 f32, 1 bf16, 2 gelu->bf16, 3 f32 resid add
template <int BN, int EPI>
__global__ __launch_bounds__(256) void gemm_bf16(
    const __bf16* __restrict__ A, int lda,
    const __bf16* __restrict__ B, int ldb, int K,
    float* __restrict__ Cf, __bf16* __restrict__ Cb, int ldc,
    const float* __restrict__ resid, int nbx) {
  constexpr int ACCN = BN / 32;
  constexpr int LB = BN / 64;
  constexpr int L = 2 + LB;
  __shared__ __align__(16) __bf16 As[3 * 4096];
  __shared__ __align__(16) __bf16 Bs[3 * BN * 32];

  int nwg = gridDim.x, id = blockIdx.x;
  int q = nwg >> 3, r = nwg & 7;
  int xcd = id & 7, pos = id >> 3;
  int nid = (xcd < r ? xcd * (q + 1) : r * (q + 1) + (xcd - r) * q) + pos;
  int row0 = (nid % nbx) * 128;
  int col0 = (nid / nbx) * BN;

  const int tid = threadIdx.x, lane = tid & 63, wid = tid >> 6;
  const int l15 = lane & 15, l4 = lane >> 4;
  const int wr = wid >> 1, wc = wid & 1;
  const int fx = (((l4 << 4) ^ (((l15 >> 1) & 3) << 4)) >> 1);

  f32x4 acc[4][ACCN];
  #pragma unroll
  for (int i = 0; i < 4; ++i)
    #pragma unroll
    for (int j = 0; j < ACCN; ++j) acc[i][j] = (f32x4){0.f, 0.f, 0.f, 0.f};

  const __bf16* aptr = A + (size_t)row0 * lda;
  const __bf16* bptr = B + (size_t)col0 * ldb;

  auto stage = [&](int t, int p) {
    #pragma unroll
    for (int i = 0; i < 2; ++i) {
      int ch = tid + 256 * i;
      int rr = ch >> 2, kc = ch & 3;
      gload_lds16(aptr + (size_t)rr * lda + t * 32 + (kc ^ ((rr >> 1) & 3)) * 8,
                  &As[p * 4096 + ch * 8]);
    }
    #pragma unroll
    for (int i = 0; i < LB; ++i) {
      int ch = tid + 256 * i;
      int rr = ch >> 2, kc = ch & 3;
      gload_lds16(bptr + (size_t)rr * ldb + t * 32 + (kc ^ ((rr >> 1) & 3)) * 8,
                  &Bs[p * BN * 32 + ch * 8]);
    }
  };

  const int NT = K >> 5;
  stage(0, 0);
  stage(1, 1);
  int p = 0;
  for (int t = 0; t < NT; ++t) {
    bool stg = (t + 2 < NT);
    if (stg) {
      int ps = p + 2; if (ps >= 3) ps -= 3;
      stage(t + 2, ps);
    }
    waitvm(stg ? 2 * L : ((t + 1 < NT) ? L : 0));
    __builtin_amdgcn_sched_barrier(0);
    __builtin_amdgcn_s_barrier();
    __builtin_amdgcn_sched_barrier(0);
    bf16x8 af[4], bfr[ACCN];
    #pragma unroll
    for (int mi = 0; mi < 4; ++mi)
      af[mi] = *(const bf16x8*)&As[p * 4096 + (wr * 64 + mi * 16 + l15) * 32 + fx];
    #pragma unroll
    for (int ni = 0; ni < ACCN; ++ni)
      bfr[ni] = *(const bf16x8*)&Bs[p * BN * 32 + (wc * (BN / 2) + ni * 16 + l15) * 32 + fx];
    __builtin_amdgcn_s_setprio(1);
    #pragma unroll
    for (int mi = 0; mi < 4; ++mi)
      #pragma unroll
      for (int ni = 0; ni < ACCN; ++ni)
        acc[mi][ni] = MFMA16(af[mi], bfr[ni], acc[mi][ni]);
    __builtin_amdgcn_s_setprio(0);
    __builtin_amdgcn_sched_barrier(0);
    __builtin_amdgcn_s_barrier();
    __builtin_amdgcn_sched_barrier(0);
    p = (p == 2) ? 0 : p + 1;
  }

  #pragma unroll
  for (int mi = 0; mi < 4; ++mi)
    #pragma unroll
    for (int ni = 0; ni < ACCN; ++ni)
      #pragma unroll
      for (int rr = 0; rr < 4; ++rr) {
        int row = row0 + wr * 64 + mi * 16 + l4 * 4 + rr;
        int col = col0 + wc * (BN / 2) + ni * 16 + l15;
        float v = acc[mi][ni][rr];
        size_t off = (size_t)row * ldc + col;
        if (EPI == 0) {
          Cf[off] = v;
        } else if (EPI == 1) {
          Cb[off] = (__bf16)v;
        } else if (EPI == 2) {
          float gv = 0.5f * v * (1.0f + erff(v * 0.70710678118654752f));
          Cb[off] = (__bf16)gv;
        } else {
          Cf[off] = resid[off] + v;
        }
      }
}

// ---------------------------------------------------------------- sliding-window attention (r12 proven version)
__global__ __launch_bounds__(256) void attn_kernel(
    const __bf16* __restrict__ qkv, __bf16* __restrict__ o) {
  const int bid = blockIdx.x;
  const int qt = bid & 15, h = (bid >> 4) & 15, b = bid >> 8;
  const int qs = qt * 64;
  const int ntiles = (qt + 1 < 5) ? (qt + 1) : 5;
  const int kt0 = qt - (ntiles - 1);

  __shared__ __align__(16) __bf16 Qs[64][72];
  __shared__ __align__(16) __bf16 KVs[64][72];
  __shared__ __align__(16) __bf16 Ssm[64][328];
  __shared__ float rsum[64];

  const int tid = threadIdx.x;
  const int lane = tid & 63, wid = tid >> 6;
  const int l15 = lane & 15, l4 = lane >> 4;
  const size_t rs = 3072;
  const __bf16* qbase = qkv + ((size_t)(b * 1024 + qs)) * rs + h * 64;

  #pragma unroll
  for (int i = 0; i < 2; ++i) {
    int c = tid * 2 + i;
    int rr = c >> 3, dc = c & 7;
    *(u32x4*)&Qs[rr][dc * 8] = *(const u32x4*)(qbase + (size_t)rr * rs + dc * 8);
  }

  for (int it = 0; it < ntiles; ++it) {
    int kt = kt0 + it;
    const __bf16* kbase = qkv + ((size_t)(b * 1024 + kt * 64)) * rs + 1024 + h * 64;
    __syncthreads();
    #pragma unroll
    for (int i = 0; i < 2; ++i) {
      int c = tid * 2 + i;
      int rr = c >> 3, dc = c & 7;
      *(u32x4*)&KVs[rr][dc * 8] = *(const u32x4*)(kbase + (size_t)rr * rs + dc * 8);
    }
    __syncthreads();
    bf16x8 aq[2];
    #pragma unroll
    for (int kk = 0; kk < 2; ++kk)
      aq[kk] = *(const bf16x8*)&Qs[16 * wid + l15][kk * 32 + l4 * 8];
    #pragma unroll
    for (int n = 0; n < 4; ++n) {
      f32x4 c4 = (f32x4){0.f, 0.f, 0.f, 0.f};
      #pragma unroll
      for (int kk = 0; kk < 2; ++kk) {
        bf16x8 bk = *(const bf16x8*)&KVs[n * 16 + l15][kk * 32 + l4 * 8];
        c4 = MFMA16(aq[kk], bk, c4);
      }
      int kj = kt * 64 + n * 16 + l15;
      int colS = it * 64 + n * 16 + l15;
      #pragma unroll
      for (int rr = 0; rr < 4; ++rr) {
        int qi = qs + 16 * wid + l4 * 4 + rr;
        int d = qi - kj;
        float sv = c4[rr] * 0.125f;
        Ssm[16 * wid + l4 * 4 + rr][colS] =
            (d >= 0 && d < 256) ? (__bf16)sv : (__bf16)(-1e30f);
      }
    }
  }
  __syncthreads();

  const int nc = ntiles * 4;
  for (int ro = 0; ro < 4; ++ro) {
    int row = 16 * wid + ro * 4 + l4;
    float vals[20];
    #pragma unroll
    for (int i = 0; i < 20; ++i) vals[i] = -3e38f;
    #pragma unroll
    for (int i = 0; i < 20; ++i)
      if (i < nc) vals[i] = (float)Ssm[row][l15 + 16 * i];
    float m = vals[0];
    #pragma unroll
    for (int i = 1; i < 20; ++i) m = fmaxf(m, vals[i]);
    #pragma unroll
    for (int off = 8; off >= 1; off >>= 1) m = fmaxf(m, __shfl_xor(m, off));
    float s = 0.f;
    #pragma unroll
    for (int i = 0; i < 20; ++i)
      if (i < nc) {
        float pp = __expf(vals[i] - m);
        s += pp;
        Ssm[row][l15 + 16 * i] = (__bf16)pp;
      }
    #pragma unroll
    for (int off = 8; off >= 1; off >>= 1) s += __shfl_xor(s, off);
    if (l15 == 0) rsum[row] = s;
  }

  f32x4 oacc[4];
  #pragma unroll
  for (int n = 0; n < 4; ++n) oacc[n] = (f32x4){0.f, 0.f, 0.f, 0.f};

  for (int it = 0; it < ntiles; ++it) {
    int kt = kt0 + it;
    const __bf16* vbase = qkv + ((size_t)(b * 1024 + kt * 64)) * rs + 2048 + h * 64;
    __syncthreads();
    {
      int k0 = (tid >> 4) * 4, d0 = (tid & 15) * 4;
      bf16x4 vr[4];
      #pragma unroll
      for (int rr = 0; rr < 4; ++rr)
        vr[rr] = *(const bf16x4*)(vbase + (size_t)(k0 + rr) * rs + d0);
      #pragma unroll
      for (int j = 0; j < 4; ++j) {
        bf16x4 wv;
        #pragma unroll
        for (int rr = 0; rr < 4; ++rr) wv[rr] = vr[rr][j];
        *(bf16x4*)&KVs[d0 + j][k0] = wv;
      }
    }
    __syncthreads();
    #pragma unroll
    for (int kk = 0; kk < 2; ++kk) {
      bf16x8 ap = *(const bf16x8*)&Ssm[16 * wid + l15][it * 64 + kk * 32 + l4 * 8];
      #pragma unroll
      for (int n = 0; n < 4; ++n) {
        bf16x8 bv = *(const bf16x8*)&KVs[n * 16 + l15][kk * 32 + l4 * 8];
        oacc[n] = MFMA16(ap, bv, oacc[n]);
      }
    }
  }

  #pragma unroll
  for (int n = 0; n < 4; ++n)
    #pragma unroll
    for (int rr = 0; rr < 4; ++rr) {
      int qrow = 16 * wid + l4 * 4 + rr;
      float inv = 1.0f / rsum[qrow];
      size_t m = (size_t)(b * 1024 + qs + qrow);
      o[m * 1024 + h * 64 + n * 16 + l15] = (__bf16)(oacc[n][rr] * inv);
    }
}

// ---------------------------------------------------------------- launch
extern "C" void kernel_launch(void* const* d_in, const int* in_sizes, int n_in,
                              void* d_out, int out_size, void* d_ws, size_t ws_size,
                              hipStream_t stream) {
  (void)in_sizes; (void)n_in; (void)out_size;
  const int*   idx     = (const int*)d_in[0];
  const float* tok_emb = (const float*)d_in[1];
  const float* pos_emb = (const float*)d_in[2];
  const float* ln1_g   = (const float*)d_in[3];
  const float* ln1_b   = (const float*)d_in[4];
  const float* qkv_w   = (const float*)d_in[5];
  const float* out_w   = (const float*)d_in[6];
  const float* ln2_g   = (const float*)d_in[7];
  const float* ln2_b   = (const float*)d_in[8];
  const float* a_w1    = (const float*)d_in[9];
  const float* a_w2    = (const float*)d_in[10];
  const float* f_w1    = (const float*)d_in[11];
  const float* f_w2    = (const float*)d_in[12];
  const float* lnf_g   = (const float*)d_in[13];
  const float* lnf_b   = (const float*)d_in[14];
  const float* head_w  = (const float*)d_in[15];
  float* out = (float*)d_out;

  char* ws = (char*)d_ws;
  float*  x    = (float*)(ws);                    // 2048x1024 f32
  __bf16* h    = (__bf16*)(ws + 8388608);         // 2048x1024 bf16
  __bf16* qkv  = (__bf16*)(ws + 12582912);        // 2048x3072 bf16
  __bf16* oatt = (__bf16*)(ws + 25165824);        // 2048x1024 bf16
  __bf16* gcat = (__bf16*)(ws + 29360128);        // 2048x4096 bf16

  const bool full = ws_size >= 313000000ull;

  __bf16 *wq, *wo, *w1c, *w2c, *wh;
  if (full) {
    wq  = (__bf16*)(ws + 46137344);   // 8x3072x1024
    wo  = (__bf16*)(ws + 96468992);   // 8x1024x1024
    w1c = (__bf16*)(ws + 113246208);  // 8x4096x1024
    w2c = (__bf16*)(ws + 180355072);  // 8x1024x4096
    wh  = (__bf16*)(ws + 247463936);  // 32000x1024
    prepack_all<<<65152, 256, 0, stream>>>(
        qkv_w, out_w, a_w1, f_w1, a_w2, f_w2, head_w, wq, wo, w1c, w2c, wh);
  } else {
    wq  = (__bf16*)(ws + 46137344);
    wo  = (__bf16*)(ws + 52428800);
    w1c = (__bf16*)(ws + 54525952);
    w2c = (__bf16*)(ws + 62914560);
    wh  = (__bf16*)(ws + 46137344);
  }

  embed_kernel<<<2048, 256, 0, stream>>>(idx, tok_emb, pos_emb, x);

  for (int l = 0; l < 8; ++l) {
    const __bf16 *wq_l, *wo_l, *w1_l, *w2_l;
    if (full) {
      wq_l = wq + (size_t)l * 3072 * 1024;
      wo_l = wo + (size_t)l * 1024 * 1024;
      w1_l = w1c + (size_t)l * 4096 * 1024;
      w2_l = w2c + (size_t)l * 1024 * 4096;
    } else {
      cvt_kernel<<<1536, 256, 0, stream>>>(qkv_w + (size_t)l * 3072 * 1024, wq, 393216);
      cvt_kernel<<<512, 256, 0, stream>>>(out_w + (size_t)l * 1024 * 1024, wo, 131072);
      cat_w1_kernel<<<2048, 256, 0, stream>>>(
          a_w1 + (size_t)l * 2048 * 1024, f_w1 + (size_t)l * 2048 * 1024, w1c);
      cat_w2_kernel<<<2048, 256, 0, stream>>>(
          a_w2 + (size_t)l * 1024 * 2048, f_w2 + (size_t)l * 1024 * 2048, w2c);
      wq_l = wq; wo_l = wo; w1_l = w1c; w2_l = w2c;
    }

    ln_kernel<<<2048, 256, 0, stream>>>(x, ln1_g + l * 1024, ln1_b + l * 1024, h);
    gemm_bf16<128, 1><<<16 * 24, 256, 0, stream>>>(
        h, 1024, wq_l, 1024, 1024, nullptr, qkv, 3072, nullptr, 16);
    attn_kernel<<<512, 256, 0, stream>>>(qkv, oatt);
    gemm_bf16<64, 3><<<16 * 16, 256, 0, stream>>>(
        oatt, 1024, wo_l, 1024, 1024, x, nullptr, 1024, x, 16);
    ln_kernel<<<2048, 256, 0, stream>>>(x, ln2_g + l * 1024, ln2_b + l * 1024, h);
    gemm_bf16<128, 2><<<16 * 32, 256, 0, stream>>>(
        h, 1024, w1_l, 1024, 1024, nullptr, gcat, 4096, nullptr, 16);
    gemm_bf16<64, 3><<<16 * 16, 256, 0, stream>>>(
        gcat, 4096, w2_l, 4096, 4096, x, nullptr, 1024, x, 16);
  }

  if (!full) {
    cvt_kernel<<<16000, 256, 0, stream>>>(head_w, wh, 4096000);
  }
  ln_kernel<<<2048, 256, 0, stream>>>(x, lnf_g, lnf_b, h);
  gemm256<0><<<8 * 125, 512, 0, stream>>>(
      h, 1024, wh, 1024, 1024, out, nullptr, 32000, 8);
}

// Round 15
// 1907.708 us; speedup vs baseline: 1.0151x; 1.0150x over previous
//
#include <hip/hip_runtime.h>

typedef __bf16 bf16x8 __attribute__((ext_vector_type(8)));
typedef __bf16 bf16x4 __attribute__((ext_vector_type(4)));
typedef float  f32x4  __attribute__((ext_vector_type(4)));
typedef unsigned int u32x4 __attribute__((ext_vector_type(4)));

#define MFMA16(a, b, c) __builtin_amdgcn_mfma_f32_16x16x32_bf16(a, b, c, 0, 0, 0)

__device__ __forceinline__ void gload_lds16(const void* g, void* l) {
  __builtin_amdgcn_global_load_lds(
      (const __attribute__((address_space(1))) void*)g,
      (__attribute__((address_space(3))) void*)l, 16, 0, 0);
}

__device__ __forceinline__ void waitvm(int vm) {
  if (vm == 6)      asm volatile("s_waitcnt vmcnt(6)" ::: "memory");
  else if (vm == 4) asm volatile("s_waitcnt vmcnt(4)" ::: "memory");
  else if (vm == 3) asm volatile("s_waitcnt vmcnt(3)" ::: "memory");
  else              asm volatile("s_waitcnt vmcnt(0)" ::: "memory");
}

__device__ __forceinline__ void cvt8(const float* __restrict__ s, __bf16* __restrict__ d) {
  f32x4 a = *(const f32x4*)s, b = *(const f32x4*)(s + 4);
  bf16x8 v;
  v[0] = (__bf16)a[0]; v[1] = (__bf16)a[1]; v[2] = (__bf16)a[2]; v[3] = (__bf16)a[3];
  v[4] = (__bf16)b[0]; v[5] = (__bf16)b[1]; v[6] = (__bf16)b[2]; v[7] = (__bf16)b[3];
  *(bf16x8*)d = v;
}

// ---------------------------------------------------------------- merged prepack (flat one-shot — best measured ~165us)
__global__ __launch_bounds__(256) void prepack_all(
    const float* __restrict__ qkv_w, const float* __restrict__ out_w,
    const float* __restrict__ a_w1, const float* __restrict__ f_w1,
    const float* __restrict__ a_w2, const float* __restrict__ f_w2,
    const float* __restrict__ head_w,
    __bf16* __restrict__ wq, __bf16* __restrict__ wo,
    __bf16* __restrict__ w1c, __bf16* __restrict__ w2c, __bf16* __restrict__ wh) {
  int i = blockIdx.x * 256 + threadIdx.x;
  if (i < 4194304) {
    if (i < 3145728) cvt8(qkv_w + ((size_t)i << 3), wq + ((size_t)i << 3));
    else {
      int j = i - 3145728;
      cvt8(out_w + ((size_t)j << 3), wo + ((size_t)j << 3));
    }
  } else if (i < 8388608) {
    int j = i - 4194304;
    int l = j >> 19, il = j & 524287;
    int k = (il & 127) * 8;
    int r = il >> 7;
    const float* s = (r < 2048)
        ? a_w1 + (size_t)l * 2097152 + ((size_t)r << 10) + k
        : f_w1 + (size_t)l * 2097152 + ((size_t)(r - 2048) << 10) + k;
    cvt8(s, w1c + ((size_t)j << 3));
  } else if (i < 12582912) {
    int j = i - 8388608;
    int l = j >> 19, il = j & 524287;
    int k = (il & 511) * 8;
    int r = il >> 9;
    const float* s = (k < 2048)
        ? a_w2 + (size_t)l * 2097152 + (size_t)r * 2048 + k
        : f_w2 + (size_t)l * 2097152 + (size_t)r * 2048 + (k - 2048);
    cvt8(s, w2c + ((size_t)j << 3));
  } else if (i < 16678912) {
    int j = i - 12582912;
    cvt8(head_w + ((size_t)j << 3), wh + ((size_t)j << 3));
  }
}

// ---------------------------------------------------------------- per-piece kernels (small-ws fallback)
__global__ __launch_bounds__(256) void cvt_kernel(
    const float* __restrict__ s, __bf16* __restrict__ d, int n8) {
  int i = blockIdx.x * 256 + threadIdx.x;
  if (i >= n8) return;
  cvt8(s + ((size_t)i << 3), d + ((size_t)i << 3));
}

__global__ __launch_bounds__(256) void cat_w1_kernel(
    const float* __restrict__ a, const float* __restrict__ f, __bf16* __restrict__ d) {
  int i = blockIdx.x * 256 + threadIdx.x;
  int k = (i & 127) * 8;
  int r = i >> 7;
  const float* s = (r < 2048) ? a + ((size_t)r << 10) + k
                              : f + ((size_t)(r - 2048) << 10) + k;
  cvt8(s, d + ((size_t)i << 3));
}

__global__ __launch_bounds__(256) void cat_w2_kernel(
    const float* __restrict__ a, const float* __restrict__ f, __bf16* __restrict__ d) {
  int i = blockIdx.x * 256 + threadIdx.x;
  int k = (i & 511) * 8;
  int r = i >> 9;
  const float* s = (k < 2048) ? a + (size_t)r * 2048 + k
                              : f + (size_t)r * 2048 + (k - 2048);
  cvt8(s, d + ((size_t)i << 3));
}

// ---------------------------------------------------------------- embed
__global__ __launch_bounds__(256) void embed_kernel(
    const int* __restrict__ idx, const float* __restrict__ te,
    const float* __restrict__ pe, float* __restrict__ x) {
  int m = blockIdx.x;
  int t = m & 1023;
  int tok = idx[m];
  int c = threadIdx.x * 4;
  f32x4 a = *(const f32x4*)(te + (size_t)tok * 1024 + c);
  f32x4 p = *(const f32x4*)(pe + (size_t)t * 1024 + c);
  *(f32x4*)(x + (size_t)m * 1024 + c) = a + p;
}

// ---------------------------------------------------------------- layernorm -> bf16
__global__ __launch_bounds__(256) void ln_kernel(
    const float* __restrict__ x, const float* __restrict__ g,
    const float* __restrict__ bb, __bf16* __restrict__ out) {
  int row = blockIdx.x, tid = threadIdx.x;
  int wid = tid >> 6, lane = tid & 63;
  f32x4 v = *(const f32x4*)(x + (size_t)row * 1024 + tid * 4);
  float s = v[0] + v[1] + v[2] + v[3];
  #pragma unroll
  for (int off = 32; off >= 1; off >>= 1) s += __shfl_xor(s, off);
  __shared__ float red1[4], red2[4];
  if (lane == 0) red1[wid] = s;
  __syncthreads();
  float mu = (red1[0] + red1[1] + red1[2] + red1[3]) * (1.0f / 1024.0f);
  float d0 = v[0] - mu, d1 = v[1] - mu, d2 = v[2] - mu, d3 = v[3] - mu;
  float q = d0 * d0 + d1 * d1 + d2 * d2 + d3 * d3;
  #pragma unroll
  for (int off = 32; off >= 1; off >>= 1) q += __shfl_xor(q, off);
  if (lane == 0) red2[wid] = q;
  __syncthreads();
  float var = (red2[0] + red2[1] + red2[2] + red2[3]) * (1.0f / 1024.0f);
  float inv = rsqrtf(var + 1e-5f);
  f32x4 gg = *(const f32x4*)(g + tid * 4);
  f32x4 bv = *(const f32x4*)(bb + tid * 4);
  bf16x4 o4;
  o4[0] = (__bf16)(d0 * inv * gg[0] + bv[0]);
  o4[1] = (__bf16)(d1 * inv * gg[1] + bv[1]);
  o4[2] = (__bf16)(d2 * inv * gg[2] + bv[2]);
  o4[3] = (__bf16)(d3 * inv * gg[3] + bv[3]);
  *(bf16x4*)(out + (size_t)row * 1024 + tid * 4) = o4;
}

// ---------------------------------------------------------------- big-tile GEMM: 256x256, BK=32, 512 thr, triple-buffered LDS (r3/r7 proven: 156us, MfmaUtil 36.7)
// C[M,N] = A[M,K] @ B[N,K]^T, all bf16 in, EPI: 0 f32, 1 bf16, 2 gelu->bf16
template <int EPI>
__global__ __launch_bounds__(512, 2) void gemm256(
    const __bf16* __restrict__ A, int lda,
    const __bf16* __restrict__ B, int ldb, int K,
    float* __restrict__ Cf, __bf16* __restrict__ Cb, int ldc, int nbx) {
  __shared__ __align__(16) __bf16 lds[49152];  // 3 bufs x (A 8192 + B 8192) elems
  const int tid = threadIdx.x, lane = tid & 63, w = tid >> 6;
  const int l15 = lane & 15, l4 = lane >> 4;
  const int wr = w >> 2, wc = w & 3;

  int nwg = gridDim.x, id = blockIdx.x;
  int q = nwg >> 3, r = nwg & 7;
  int xcd = id & 7, pos = id >> 3;
  int nid = (xcd < r ? xcd * (q + 1) : r * (q + 1) + (xcd - r) * q) + pos;
  int row0 = (nid % nbx) * 256, col0 = (nid / nbx) * 256;

  const __bf16* ag = A + (size_t)row0 * lda;
  const __bf16* bg = B + (size_t)col0 * ldb;

  f32x4 acc[8][4];
  #pragma unroll
  for (int i = 0; i < 8; ++i)
    #pragma unroll
    for (int j = 0; j < 4; ++j) acc[i][j] = (f32x4){0.f, 0.f, 0.f, 0.f};

  int srow[2], scol[2];
  #pragma unroll
  for (int i = 0; i < 2; ++i) {
    int p = (w + i * 8) * 1024 + lane * 16;   // byte within 16 KB half
    int row = p >> 6, ch = (p >> 4) & 3;
    srow[i] = row;
    scol[i] = (ch ^ ((row >> 1) & 3)) * 8;    // pre-swizzled source chunk
  }
  const int fx = (((l4 << 4) ^ (((l15 >> 1) & 3) << 4)) >> 1);  // swizzled frag col (elems)

  auto stageA = [&](int t, int c) {
    #pragma unroll
    for (int i = 0; i < 2; ++i)
      gload_lds16(ag + (size_t)srow[i] * lda + t * 32 + scol[i],
                  &lds[c * 16384 + (w + i * 8) * 512]);
  };
  auto stageB = [&](int t, int c) {
    #pragma unroll
    for (int i = 0; i < 2; ++i)
      gload_lds16(bg + (size_t)srow[i] * ldb + t * 32 + scol[i],
                  &lds[c * 16384 + 8192 + (w + i * 8) * 512]);
  };

  auto kgroup = [&](int t2, int c, int cn, int vm, bool stg) {
    if (stg) stageA(t2, cn);
    waitvm(vm);
    __builtin_amdgcn_sched_barrier(0);
    __builtin_amdgcn_s_barrier();
    __builtin_amdgcn_sched_barrier(0);
    const int cb = c * 16384;
    bf16x8 bfr[4], af[4];
    #pragma unroll
    for (int ni = 0; ni < 4; ++ni)
      bfr[ni] = *(const bf16x8*)&lds[cb + 8192 + (wc * 64 + ni * 16 + l15) * 32 + fx];
    #pragma unroll
    for (int mi = 0; mi < 4; ++mi)
      af[mi] = *(const bf16x8*)&lds[cb + (wr * 128 + mi * 16 + l15) * 32 + fx];
    __builtin_amdgcn_s_setprio(1);
    #pragma unroll
    for (int mi = 0; mi < 4; ++mi)
      #pragma unroll
      for (int ni = 0; ni < 4; ++ni)
        acc[mi][ni] = MFMA16(af[mi], bfr[ni], acc[mi][ni]);
    __builtin_amdgcn_s_setprio(0);
    // phase 2: upper row-half
    #pragma unroll
    for (int mi = 0; mi < 4; ++mi)
      af[mi] = *(const bf16x8*)&lds[cb + (wr * 128 + (mi + 4) * 16 + l15) * 32 + fx];
    if (stg) stageB(t2, cn);
    __builtin_amdgcn_s_setprio(1);
    #pragma unroll
    for (int mi = 0; mi < 4; ++mi)
      #pragma unroll
      for (int ni = 0; ni < 4; ++ni)
        acc[mi + 4][ni] = MFMA16(af[mi], bfr[ni], acc[mi + 4][ni]);
    __builtin_amdgcn_s_setprio(0);
    __builtin_amdgcn_sched_barrier(0);
    __builtin_amdgcn_s_barrier();
    __builtin_amdgcn_sched_barrier(0);
  };

  const int NT = K >> 5;
  // prologue: tiles 0 and 1
  stageA(0, 0); stageB(0, 0);
  stageA(1, 1); stageB(1, 1);

  int c = 0;
  for (int t = 0; t < NT - 2; ++t) {
    int cn = c + 2; if (cn >= 3) cn -= 3;
    kgroup(t + 2, c, cn, 6, true);
    c = (c == 2) ? 0 : c + 1;
  }
  kgroup(0, c, 0, 4, false);
  c = (c == 2) ? 0 : c + 1;
  kgroup(0, c, 0, 0, false);

  #pragma unroll
  for (int mi = 0; mi < 8; ++mi)
    #pragma unroll
    for (int ni = 0; ni < 4; ++ni)
      #pragma unroll
      for (int rr = 0; rr < 4; ++rr) {
        int row = row0 + wr * 128 + mi * 16 + l4 * 4 + rr;
        int col = col0 + wc * 64 + ni * 16 + l15;
        float v = acc[mi][ni][rr];
        size_t off = (size_t)row * ldc + col;
        if (EPI == 0) {
          Cf[off] = v;
        } else if (EPI == 1) {
          Cb[off] = (__bf16)v;
        } else {
          float gv = 0.5f * v * (1.0f + erff(v * 0.70710678118654752f));
          Cb[off] = (__bf16)gv;
        }
      }
}

// ---------------------------------------------------------------- 128-tile GEMM, 3-buffer 2-ahead counted-vmcnt
// EPI: 0 f32, 1 bf16, 2 gelu->bf16, 3 f32 resid add
template <int BN, int EPI>
__global__ __launch_bounds__(256) void gemm_bf16(
    const __bf16* __restrict__ A, int lda,
    const __bf16* __restrict__ B, int ldb, int K,
    float* __restrict__ Cf, __bf16* __restrict__ Cb, int ldc,
    const float* __restrict__ resid, int nbx) {
  constexpr int ACCN = BN / 32;
  constexpr int LB = BN / 64;
  constexpr int L = 2 + LB;
  __shared__ __align__(16) __bf16 As[3 * 4096];
  __shared__ __align__(16) __bf16 Bs[3 * BN * 32];

  int nwg = gridDim.x, id = blockIdx.x;
  int q = nwg >> 3, r = nwg & 7;
  int xcd = id & 7, pos = id >> 3;
  int nid = (xcd < r ? xcd * (q + 1) : r * (q + 1) + (xcd - r) * q) + pos;
  int row0 = (nid % nbx) * 128;
  int col0 = (nid / nbx) * BN;

  const int tid = threadIdx.x, lane = tid & 63, wid = tid >> 6;
  const int l15 = lane & 15, l4 = lane >> 4;
  const int wr = wid >> 1, wc = wid & 1;
  const int fx = (((l4 << 4) ^ (((l15 >> 1) & 3) << 4)) >> 1);

  f32x4 acc[4][ACCN];
  #pragma unroll
  for (int i = 0; i < 4; ++i)
    #pragma unroll
    for (int j = 0; j < ACCN; ++j) acc[i][j] = (f32x4){0.f, 0.f, 0.f, 0.f};

  const __bf16* aptr = A + (size_t)row0 * lda;
  const __bf16* bptr = B + (size_t)col0 * ldb;

  auto stage = [&](int t, int p) {
    #pragma unroll
    for (int i = 0; i < 2; ++i) {
      int ch = tid + 256 * i;
      int rr = ch >> 2, kc = ch & 3;
      gload_lds16(aptr + (size_t)rr * lda + t * 32 + (kc ^ ((rr >> 1) & 3)) * 8,
                  &As[p * 4096 + ch * 8]);
    }
    #pragma unroll
    for (int i = 0; i < LB; ++i) {
      int ch = tid + 256 * i;
      int rr = ch >> 2, kc = ch & 3;
      gload_lds16(bptr + (size_t)rr * ldb + t * 32 + (kc ^ ((rr >> 1) & 3)) * 8,
                  &Bs[p * BN * 32 + ch * 8]);
    }
  };

  const int NT = K >> 5;
  stage(0, 0);
  stage(1, 1);
  int p = 0;
  for (int t = 0; t < NT; ++t) {
    bool stg = (t + 2 < NT);
    if (stg) {
      int ps = p + 2; if (ps >= 3) ps -= 3;
      stage(t + 2, ps);
    }
    waitvm(stg ? 2 * L : ((t + 1 < NT) ? L : 0));
    __builtin_amdgcn_sched_barrier(0);
    __builtin_amdgcn_s_barrier();
    __builtin_amdgcn_sched_barrier(0);
    bf16x8 af[4], bfr[ACCN];
    #pragma unroll
    for (int mi = 0; mi < 4; ++mi)
      af[mi] = *(const bf16x8*)&As[p * 4096 + (wr * 64 + mi * 16 + l15) * 32 + fx];
    #pragma unroll
    for (int ni = 0; ni < ACCN; ++ni)
      bfr[ni] = *(const bf16x8*)&Bs[p * BN * 32 + (wc * (BN / 2) + ni * 16 + l15) * 32 + fx];
    __builtin_amdgcn_s_setprio(1);
    #pragma unroll
    for (int mi = 0; mi < 4; ++mi)
      #pragma unroll
      for (int ni = 0; ni < ACCN; ++ni)
        acc[mi][ni] = MFMA16(af[mi], bfr[ni], acc[mi][ni]);
    __builtin_amdgcn_s_setprio(0);
    __builtin_amdgcn_sched_barrier(0);
    __builtin_amdgcn_s_barrier();
    __builtin_amdgcn_sched_barrier(0);
    p = (p == 2) ? 0 : p + 1;
  }

  #pragma unroll
  for (int mi = 0; mi < 4; ++mi)
    #pragma unroll
    for (int ni = 0; ni < ACCN; ++ni)
      #pragma unroll
      for (int rr = 0; rr < 4; ++rr) {
        int row = row0 + wr * 64 + mi * 16 + l4 * 4 + rr;
        int col = col0 + wc * (BN / 2) + ni * 16 + l15;
        float v = acc[mi][ni][rr];
        size_t off = (size_t)row * ldc + col;
        if (EPI == 0) {
          Cf[off] = v;
        } else if (EPI == 1) {
          Cb[off] = (__bf16)v;
        } else if (EPI == 2) {
          float gv = 0.5f * v * (1.0f + erff(v * 0.70710678118654752f));
          Cb[off] = (__bf16)gv;
        } else {
          Cf[off] = resid[off] + v;
        }
      }
}

// ---------------------------------------------------------------- sliding-window attention (r12 proven version)
__global__ __launch_bounds__(256) void attn_kernel(
    const __bf16* __restrict__ qkv, __bf16* __restrict__ o) {
  const int bid = blockIdx.x;
  const int qt = bid & 15, h = (bid >> 4) & 15, b = bid >> 8;
  const int qs = qt * 64;
  const int ntiles = (qt + 1 < 5) ? (qt + 1) : 5;
  const int kt0 = qt - (ntiles - 1);

  __shared__ __align__(16) __bf16 Qs[64][72];
  __shared__ __align__(16) __bf16 KVs[64][72];
  __shared__ __align__(16) __bf16 Ssm[64][328];
  __shared__ float rsum[64];

  const int tid = threadIdx.x;
  const int lane = tid & 63, wid = tid >> 6;
  const int l15 = lane & 15, l4 = lane >> 4;
  const size_t rs = 3072;
  const __bf16* qbase = qkv + ((size_t)(b * 1024 + qs)) * rs + h * 64;

  #pragma unroll
  for (int i = 0; i < 2; ++i) {
    int c = tid * 2 + i;
    int rr = c >> 3, dc = c & 7;
    *(u32x4*)&Qs[rr][dc * 8] = *(const u32x4*)(qbase + (size_t)rr * rs + dc * 8);
  }

  for (int it = 0; it < ntiles; ++it) {
    int kt = kt0 + it;
    const __bf16* kbase = qkv + ((size_t)(b * 1024 + kt * 64)) * rs + 1024 + h * 64;
    __syncthreads();
    #pragma unroll
    for (int i = 0; i < 2; ++i) {
      int c = tid * 2 + i;
      int rr = c >> 3, dc = c & 7;
      *(u32x4*)&KVs[rr][dc * 8] = *(const u32x4*)(kbase + (size_t)rr * rs + dc * 8);
    }
    __syncthreads();
    bf16x8 aq[2];
    #pragma unroll
    for (int kk = 0; kk < 2; ++kk)
      aq[kk] = *(const bf16x8*)&Qs[16 * wid + l15][kk * 32 + l4 * 8];
    #pragma unroll
    for (int n = 0; n < 4; ++n) {
      f32x4 c4 = (f32x4){0.f, 0.f, 0.f, 0.f};
      #pragma unroll
      for (int kk = 0; kk < 2; ++kk) {
        bf16x8 bk = *(const bf16x8*)&KVs[n * 16 + l15][kk * 32 + l4 * 8];
        c4 = MFMA16(aq[kk], bk, c4);
      }
      int kj = kt * 64 + n * 16 + l15;
      int colS = it * 64 + n * 16 + l15;
      #pragma unroll
      for (int rr = 0; rr < 4; ++rr) {
        int qi = qs + 16 * wid + l4 * 4 + rr;
        int d = qi - kj;
        float sv = c4[rr] * 0.125f;
        Ssm[16 * wid + l4 * 4 + rr][colS] =
            (d >= 0 && d < 256) ? (__bf16)sv : (__bf16)(-1e30f);
      }
    }
  }
  __syncthreads();

  const int nc = ntiles * 4;
  for (int ro = 0; ro < 4; ++ro) {
    int row = 16 * wid + ro * 4 + l4;
    float vals[20];
    #pragma unroll
    for (int i = 0; i < 20; ++i) vals[i] = -3e38f;
    #pragma unroll
    for (int i = 0; i < 20; ++i)
      if (i < nc) vals[i] = (float)Ssm[row][l15 + 16 * i];
    float m = vals[0];
    #pragma unroll
    for (int i = 1; i < 20; ++i) m = fmaxf(m, vals[i]);
    #pragma unroll
    for (int off = 8; off >= 1; off >>= 1) m = fmaxf(m, __shfl_xor(m, off));
    float s = 0.f;
    #pragma unroll
    for (int i = 0; i < 20; ++i)
      if (i < nc) {
        float pp = __expf(vals[i] - m);
        s += pp;
        Ssm[row][l15 + 16 * i] = (__bf16)pp;
      }
    #pragma unroll
    for (int off = 8; off >= 1; off >>= 1) s += __shfl_xor(s, off);
    if (l15 == 0) rsum[row] = s;
  }

  f32x4 oacc[4];
  #pragma unroll
  for (int n = 0; n < 4; ++n) oacc[n] = (f32x4){0.f, 0.f, 0.f, 0.f};

  for (int it = 0; it < ntiles; ++it) {
    int kt = kt0 + it;
    const __bf16* vbase = qkv + ((size_t)(b * 1024 + kt * 64)) * rs + 2048 + h * 64;
    __syncthreads();
    {
      int k0 = (tid >> 4) * 4, d0 = (tid & 15) * 4;
      bf16x4 vr[4];
      #pragma unroll
      for (int rr = 0; rr < 4; ++rr)
        vr[rr] = *(const bf16x4*)(vbase + (size_t)(k0 + rr) * rs + d0);
      #pragma unroll
      for (int j = 0; j < 4; ++j) {
        bf16x4 wv;
        #pragma unroll
        for (int rr = 0; rr < 4; ++rr) wv[rr] = vr[rr][j];
        *(bf16x4*)&KVs[d0 + j][k0] = wv;
      }
    }
    __syncthreads();
    #pragma unroll
    for (int kk = 0; kk < 2; ++kk) {
      bf16x8 ap = *(const bf16x8*)&Ssm[16 * wid + l15][it * 64 + kk * 32 + l4 * 8];
      #pragma unroll
      for (int n = 0; n < 4; ++n) {
        bf16x8 bv = *(const bf16x8*)&KVs[n * 16 + l15][kk * 32 + l4 * 8];
        oacc[n] = MFMA16(ap, bv, oacc[n]);
      }
    }
  }

  #pragma unroll
  for (int n = 0; n < 4; ++n)
    #pragma unroll
    for (int rr = 0; rr < 4; ++rr) {
      int qrow = 16 * wid + l4 * 4 + rr;
      float inv = 1.0f / rsum[qrow];
      size_t m = (size_t)(b * 1024 + qs + qrow);
      o[m * 1024 + h * 64 + n * 16 + l15] = (__bf16)(oacc[n][rr] * inv);
    }
}

// ---------------------------------------------------------------- launch
extern "C" void kernel_launch(void* const* d_in, const int* in_sizes, int n_in,
                              void* d_out, int out_size, void* d_ws, size_t ws_size,
                              hipStream_t stream) {
  (void)in_sizes; (void)n_in; (void)out_size;
  const int*   idx     = (const int*)d_in[0];
  const float* tok_emb = (const float*)d_in[1];
  const float* pos_emb = (const float*)d_in[2];
  const float* ln1_g   = (const float*)d_in[3];
  const float* ln1_b   = (const float*)d_in[4];
  const float* qkv_w   = (const float*)d_in[5];
  const float* out_w   = (const float*)d_in[6];
  const float* ln2_g   = (const float*)d_in[7];
  const float* ln2_b   = (const float*)d_in[8];
  const float* a_w1    = (const float*)d_in[9];
  const float* a_w2    = (const float*)d_in[10];
  const float* f_w1    = (const float*)d_in[11];
  const float* f_w2    = (const float*)d_in[12];
  const float* lnf_g   = (const float*)d_in[13];
  const float* lnf_b   = (const float*)d_in[14];
  const float* head_w  = (const float*)d_in[15];
  float* out = (float*)d_out;

  char* ws = (char*)d_ws;
  float*  x    = (float*)(ws);                    // 2048x1024 f32
  __bf16* h    = (__bf16*)(ws + 8388608);         // 2048x1024 bf16
  __bf16* qkv  = (__bf16*)(ws + 12582912);        // 2048x3072 bf16
  __bf16* oatt = (__bf16*)(ws + 25165824);        // 2048x1024 bf16
  __bf16* gcat = (__bf16*)(ws + 29360128);        // 2048x4096 bf16

  const bool full = ws_size >= 313000000ull;

  __bf16 *wq, *wo, *w1c, *w2c, *wh;
  if (full) {
    wq  = (__bf16*)(ws + 46137344);   // 8x3072x1024
    wo  = (__bf16*)(ws + 96468992);   // 8x1024x1024
    w1c = (__bf16*)(ws + 113246208);  // 8x4096x1024
    w2c = (__bf16*)(ws + 180355072);  // 8x1024x4096
    wh  = (__bf16*)(ws + 247463936);  // 32000x1024
    prepack_all<<<65152, 256, 0, stream>>>(
        qkv_w, out_w, a_w1, f_w1, a_w2, f_w2, head_w, wq, wo, w1c, w2c, wh);
  } else {
    wq  = (__bf16*)(ws + 46137344);
    wo  = (__bf16*)(ws + 52428800);
    w1c = (__bf16*)(ws + 54525952);
    w2c = (__bf16*)(ws + 62914560);
    wh  = (__bf16*)(ws + 46137344);
  }

  embed_kernel<<<2048, 256, 0, stream>>>(idx, tok_emb, pos_emb, x);

  for (int l = 0; l < 8; ++l) {
    const __bf16 *wq_l, *wo_l, *w1_l, *w2_l;
    if (full) {
      wq_l = wq + (size_t)l * 3072 * 1024;
      wo_l = wo + (size_t)l * 1024 * 1024;
      w1_l = w1c + (size_t)l * 4096 * 1024;
      w2_l = w2c + (size_t)l * 1024 * 4096;
    } else {
      cvt_kernel<<<1536, 256, 0, stream>>>(qkv_w + (size_t)l * 3072 * 1024, wq, 393216);
      cvt_kernel<<<512, 256, 0, stream>>>(out_w + (size_t)l * 1024 * 1024, wo, 131072);
      cat_w1_kernel<<<2048, 256, 0, stream>>>(
          a_w1 + (size_t)l * 2048 * 1024, f_w1 + (size_t)l * 2048 * 1024, w1c);
      cat_w2_kernel<<<2048, 256, 0, stream>>>(
          a_w2 + (size_t)l * 1024 * 2048, f_w2 + (size_t)l * 1024 * 2048, w2c);
      wq_l = wq; wo_l = wo; w1_l = w1c; w2_l = w2c;
    }

    ln_kernel<<<2048, 256, 0, stream>>>(x, ln1_g + l * 1024, ln1_b + l * 1024, h);
    gemm_bf16<128, 1><<<16 * 24, 256, 0, stream>>>(
        h, 1024, wq_l, 1024, 1024, nullptr, qkv, 3072, nullptr, 16);
    attn_kernel<<<512, 256, 0, stream>>>(qkv, oatt);
    gemm_bf16<64, 3><<<16 * 16, 256, 0, stream>>>(
        oatt, 1024, wo_l, 1024, 1024, x, nullptr, 1024, x, 16);
    ln_kernel<<<2048, 256, 0, stream>>>(x, ln2_g + l * 1024, ln2_b + l * 1024, h);
    gemm_bf16<128, 2><<<16 * 32, 256, 0, stream>>>(
        h, 1024, w1_l, 1024, 1024, nullptr, gcat, 4096, nullptr, 16);
    gemm_bf16<64, 3><<<16 * 16, 256, 0, stream>>>(
        gcat, 4096, w2_l, 4096, 4096, x, nullptr, 1024, x, 16);
  }

  if (!full) {
    cvt_kernel<<<16000, 256, 0, stream>>>(head_w, wh, 4096000);
  }
  ln_kernel<<<2048, 256, 0, stream>>>(x, lnf_g, lnf_b, h);
  gemm256<0><<<8 * 125, 512, 0, stream>>>(
      h, 1024, wh, 1024, 1024, out, nullptr, 32000, 8);
}

// Round 16
// 1900.000 us; speedup vs baseline: 1.0192x; 1.0041x over previous
//
#include <hip/hip_runtime.h>

typedef __bf16 bf16x8 __attribute__((ext_vector_type(8)));
typedef __bf16 bf16x4 __attribute__((ext_vector_type(4)));
typedef float  f32x4  __attribute__((ext_vector_type(4)));
typedef unsigned int u32x4 __attribute__((ext_vector_type(4)));

#define MFMA16(a, b, c) __builtin_amdgcn_mfma_f32_16x16x32_bf16(a, b, c, 0, 0, 0)

__device__ __forceinline__ void gload_lds16(const void* g, void* l) {
  __builtin_amdgcn_global_load_lds(
      (const __attribute__((address_space(1))) void*)g,
      (__attribute__((address_space(3))) void*)l, 16, 0, 0);
}

__device__ __forceinline__ void waitvm(int vm) {
  if (vm == 6)      asm volatile("s_waitcnt vmcnt(6)" ::: "memory");
  else if (vm == 4) asm volatile("s_waitcnt vmcnt(4)" ::: "memory");
  else if (vm == 3) asm volatile("s_waitcnt vmcnt(3)" ::: "memory");
  else              asm volatile("s_waitcnt vmcnt(0)" ::: "memory");
}

__device__ __forceinline__ void cvt8(const float* __restrict__ s, __bf16* __restrict__ d) {
  f32x4 a = *(const f32x4*)s, b = *(const f32x4*)(s + 4);
  bf16x8 v;
  v[0] = (__bf16)a[0]; v[1] = (__bf16)a[1]; v[2] = (__bf16)a[2]; v[3] = (__bf16)a[3];
  v[4] = (__bf16)b[0]; v[5] = (__bf16)b[1]; v[6] = (__bf16)b[2]; v[7] = (__bf16)b[3];
  *(bf16x8*)d = v;
}

// ---------------------------------------------------------------- merged prepack (flat one-shot — best measured ~165us)
__global__ __launch_bounds__(256) void prepack_all(
    const float* __restrict__ qkv_w, const float* __restrict__ out_w,
    const float* __restrict__ a_w1, const float* __restrict__ f_w1,
    const float* __restrict__ a_w2, const float* __restrict__ f_w2,
    const float* __restrict__ head_w,
    __bf16* __restrict__ wq, __bf16* __restrict__ wo,
    __bf16* __restrict__ w1c, __bf16* __restrict__ w2c, __bf16* __restrict__ wh) {
  int i = blockIdx.x * 256 + threadIdx.x;
  if (i < 4194304) {
    if (i < 3145728) cvt8(qkv_w + ((size_t)i << 3), wq + ((size_t)i << 3));
    else {
      int j = i - 3145728;
      cvt8(out_w + ((size_t)j << 3), wo + ((size_t)j << 3));
    }
  } else if (i < 8388608) {
    int j = i - 4194304;
    int l = j >> 19, il = j & 524287;
    int k = (il & 127) * 8;
    int r = il >> 7;
    const float* s = (r < 2048)
        ? a_w1 + (size_t)l * 2097152 + ((size_t)r << 10) + k
        : f_w1 + (size_t)l * 2097152 + ((size_t)(r - 2048) << 10) + k;
    cvt8(s, w1c + ((size_t)j << 3));
  } else if (i < 12582912) {
    int j = i - 8388608;
    int l = j >> 19, il = j & 524287;
    int k = (il & 511) * 8;
    int r = il >> 9;
    const float* s = (k < 2048)
        ? a_w2 + (size_t)l * 2097152 + (size_t)r * 2048 + k
        : f_w2 + (size_t)l * 2097152 + (size_t)r * 2048 + (k - 2048);
    cvt8(s, w2c + ((size_t)j << 3));
  } else if (i < 16678912) {
    int j = i - 12582912;
    cvt8(head_w + ((size_t)j << 3), wh + ((size_t)j << 3));
  }
}

// ---------------------------------------------------------------- per-piece kernels (small-ws fallback)
__global__ __launch_bounds__(256) void cvt_kernel(
    const float* __restrict__ s, __bf16* __restrict__ d, int n8) {
  int i = blockIdx.x * 256 + threadIdx.x;
  if (i >= n8) return;
  cvt8(s + ((size_t)i << 3), d + ((size_t)i << 3));
}

__global__ __launch_bounds__(256) void cat_w1_kernel(
    const float* __restrict__ a, const float* __restrict__ f, __bf16* __restrict__ d) {
  int i = blockIdx.x * 256 + threadIdx.x;
  int k = (i & 127) * 8;
  int r = i >> 7;
  const float* s = (r < 2048) ? a + ((size_t)r << 10) + k
                              : f + ((size_t)(r - 2048) << 10) + k;
  cvt8(s, d + ((size_t)i << 3));
}

__global__ __launch_bounds__(256) void cat_w2_kernel(
    const float* __restrict__ a, const float* __restrict__ f, __bf16* __restrict__ d) {
  int i = blockIdx.x * 256 + threadIdx.x;
  int k = (i & 511) * 8;
  int r = i >> 9;
  const float* s = (k < 2048) ? a + (size_t)r * 2048 + k
                              : f + (size_t)r * 2048 + (k - 2048);
  cvt8(s, d + ((size_t)i << 3));
}

// ---------------------------------------------------------------- embed
__global__ __launch_bounds__(256) void embed_kernel(
    const int* __restrict__ idx, const float* __restrict__ te,
    const float* __restrict__ pe, float* __restrict__ x) {
  int m = blockIdx.x;
  int t = m & 1023;
  int tok = idx[m];
  int c = threadIdx.x * 4;
  f32x4 a = *(const f32x4*)(te + (size_t)tok * 1024 + c);
  f32x4 p = *(const f32x4*)(pe + (size_t)t * 1024 + c);
  *(f32x4*)(x + (size_t)m * 1024 + c) = a + p;
}

// ---------------------------------------------------------------- layernorm -> bf16
__global__ __launch_bounds__(256) void ln_kernel(
    const float* __restrict__ x, const float* __restrict__ g,
    const float* __restrict__ bb, __bf16* __restrict__ out) {
  int row = blockIdx.x, tid = threadIdx.x;
  int wid = tid >> 6, lane = tid & 63;
  f32x4 v = *(const f32x4*)(x + (size_t)row * 1024 + tid * 4);
  float s = v[0] + v[1] + v[2] + v[3];
  #pragma unroll
  for (int off = 32; off >= 1; off >>= 1) s += __shfl_xor(s, off);
  __shared__ float red1[4], red2[4];
  if (lane == 0) red1[wid] = s;
  __syncthreads();
  float mu = (red1[0] + red1[1] + red1[2] + red1[3]) * (1.0f / 1024.0f);
  float d0 = v[0] - mu, d1 = v[1] - mu, d2 = v[2] - mu, d3 = v[3] - mu;
  float q = d0 * d0 + d1 * d1 + d2 * d2 + d3 * d3;
  #pragma unroll
  for (int off = 32; off >= 1; off >>= 1) q += __shfl_xor(q, off);
  if (lane == 0) red2[wid] = q;
  __syncthreads();
  float var = (red2[0] + red2[1] + red2[2] + red2[3]) * (1.0f / 1024.0f);
  float inv = rsqrtf(var + 1e-5f);
  f32x4 gg = *(const f32x4*)(g + tid * 4);
  f32x4 bv = *(const f32x4*)(bb + tid * 4);
  bf16x4 o4;
  o4[0] = (__bf16)(d0 * inv * gg[0] + bv[0]);
  o4[1] = (__bf16)(d1 * inv * gg[1] + bv[1]);
  o4[2] = (__bf16)(d2 * inv * gg[2] + bv[2]);
  o4[3] = (__bf16)(d3 * inv * gg[3] + bv[3]);
  *(bf16x4*)(out + (size_t)row * 1024 + tid * 4) = o4;
}

// ---------------------------------------------------------------- big-tile GEMM: 256x256, BK=64, 512 thr, double-buffered LDS (128 KB)
// Same kgroup skeleton as r3/r7 but one barrier-pair per 64 K-cols (64 MFMA/pair,
// half the barrier rate). Counted vmcnt(4) steady state. XOR-8-chunk swizzle.
// C[M,N] = A[M,K] @ B[N,K]^T, all bf16 in, EPI: 0 f32, 1 bf16, 2 gelu->bf16
template <int EPI>
__global__ __launch_bounds__(512, 2) void gemm256(
    const __bf16* __restrict__ A, int lda,
    const __bf16* __restrict__ B, int ldb, int K,
    float* __restrict__ Cf, __bf16* __restrict__ Cb, int ldc, int nbx) {
  __shared__ __align__(16) __bf16 lds[65536];  // 2 bufs x (A 16384 + B 16384) elems
  const int tid = threadIdx.x, lane = tid & 63, w = tid >> 6;
  const int l15 = lane & 15, l4 = lane >> 4;
  const int wr = w >> 2, wc = w & 3;

  int nwg = gridDim.x, id = blockIdx.x;
  int q = nwg >> 3, r = nwg & 7;
  int xcd = id & 7, pos = id >> 3;
  int nid = (xcd < r ? xcd * (q + 1) : r * (q + 1) + (xcd - r) * q) + pos;
  int row0 = (nid % nbx) * 256, col0 = (nid / nbx) * 256;

  const __bf16* ag = A + (size_t)row0 * lda;
  const __bf16* bg = B + (size_t)col0 * ldb;

  f32x4 acc[8][4];
  #pragma unroll
  for (int i = 0; i < 8; ++i)
    #pragma unroll
    for (int j = 0; j < 4; ++j) acc[i][j] = (f32x4){0.f, 0.f, 0.f, 0.f};

  // staging constants: load i covers chunk index (i*512 + tid) of a 16384-elem half
  int srow[4], scol[4];
  #pragma unroll
  for (int i = 0; i < 4; ++i) {
    int v = i * 512 + tid;
    int row = v >> 3, ch = v & 7;
    srow[i] = row;
    scol[i] = (ch ^ (row & 7)) * 8;   // pre-swizzled source column (elems)
  }
  // fragment chunk offsets for kk=0/1 (elems); frag row = ..+l15 so row&7 == l15&7
  const int fx0 = ((0 * 4 + l4) ^ (l15 & 7)) << 3;
  const int fx1 = ((1 * 4 + l4) ^ (l15 & 7)) << 3;

  auto stageA = [&](int t, int b) {
    #pragma unroll
    for (int i = 0; i < 4; ++i)
      gload_lds16(ag + (size_t)srow[i] * lda + t * 64 + scol[i],
                  &lds[b * 32768 + (i * 512 + tid) * 8]);
  };
  auto stageB = [&](int t, int b) {
    #pragma unroll
    for (int i = 0; i < 4; ++i)
      gload_lds16(bg + (size_t)srow[i] * ldb + t * 64 + scol[i],
                  &lds[b * 32768 + 16384 + (i * 512 + tid) * 8]);
  };
  auto bar = [&]() {
    __builtin_amdgcn_sched_barrier(0);
    __builtin_amdgcn_s_barrier();
    __builtin_amdgcn_sched_barrier(0);
  };

  const int NT = K >> 6;
  stageA(0, 0); stageB(0, 0);

  for (int t = 0; t < NT; ++t) {
    const int bf = t & 1, bn = bf ^ 1;
    const bool stg = (t + 1 < NT);
    if (stg) stageA(t + 1, bn);
    // in-flight: A(t)4 + B(t)4 + A(t+1)4 = 12 -> drain tile t's 8
    waitvm(stg ? 4 : 0);
    bar();
    const int ab = bf * 32768, bb2 = ab + 16384;
    bf16x8 af[4], bfr[4];
    #pragma unroll
    for (int kk = 0; kk < 2; ++kk) {
      const int fx = kk ? fx1 : fx0;
      #pragma unroll
      for (int ni = 0; ni < 4; ++ni)
        bfr[ni] = *(const bf16x8*)&lds[bb2 + (wc * 64 + ni * 16 + l15) * 64 + fx];
      #pragma unroll
      for (int mi = 0; mi < 4; ++mi)
        af[mi] = *(const bf16x8*)&lds[ab + (wr * 128 + mi * 16 + l15) * 64 + fx];
      __builtin_amdgcn_s_setprio(1);
      #pragma unroll
      for (int mi = 0; mi < 4; ++mi)
        #pragma unroll
        for (int ni = 0; ni < 4; ++ni)
          acc[mi][ni] = MFMA16(af[mi], bfr[ni], acc[mi][ni]);
      __builtin_amdgcn_s_setprio(0);
      #pragma unroll
      for (int mi = 0; mi < 4; ++mi)
        af[mi] = *(const bf16x8*)&lds[ab + (wr * 128 + (mi + 4) * 16 + l15) * 64 + fx];
      if (kk == 0 && stg) stageB(t + 1, bn);
      __builtin_amdgcn_s_setprio(1);
      #pragma unroll
      for (int mi = 0; mi < 4; ++mi)
        #pragma unroll
        for (int ni = 0; ni < 4; ++ni)
          acc[mi + 4][ni] = MFMA16(af[mi], bfr[ni], acc[mi + 4][ni]);
      __builtin_amdgcn_s_setprio(0);
    }
    bar();
  }

  #pragma unroll
  for (int mi = 0; mi < 8; ++mi)
    #pragma unroll
    for (int ni = 0; ni < 4; ++ni)
      #pragma unroll
      for (int rr = 0; rr < 4; ++rr) {
        int row = row0 + wr * 128 + mi * 16 + l4 * 4 + rr;
        int col = col0 + wc * 64 + ni * 16 + l15;
        float v = acc[mi][ni][rr];
        size_t off = (size_t)row * ldc + col;
        if (EPI == 0) {
          Cf[off] = v;
        } else if (EPI == 1) {
          Cb[off] = (__bf16)v;
        } else {
          float gv = 0.5f * v * (1.0f + erff(v * 0.70710678118654752f));
          Cb[off] = (__bf16)gv;
        }
      }
}

// ---------------------------------------------------------------- 128-tile GEMM, 3-buffer 2-ahead counted-vmcnt
// EPI: 0 f32, 1 bf16, 2 gelu->bf16, 3 f32 resid add
template <int BN, int EPI>
__global__ __launch_bounds__(256) void gemm_bf16(
    const __bf16* __restrict__ A, int lda,
    const __bf16* __restrict__ B, int ldb, int K,
    float* __restrict__ Cf, __bf16* __restrict__ Cb, int ldc,
    const float* __restrict__ resid, int nbx) {
  constexpr int ACCN = BN / 32;
  constexpr int LB = BN / 64;
  constexpr int L = 2 + LB;
  __shared__ __align__(16) __bf16 As[3 * 4096];
  __shared__ __align__(16) __bf16 Bs[3 * BN * 32];

  int nwg = gridDim.x, id = blockIdx.x;
  int q = nwg >> 3, r = nwg & 7;
  int xcd = id & 7, pos = id >> 3;
  int nid = (xcd < r ? xcd * (q + 1) : r * (q + 1) + (xcd - r) * q) + pos;
  int row0 = (nid % nbx) * 128;
  int col0 = (nid / nbx) * BN;

  const int tid = threadIdx.x, lane = tid & 63, wid = tid >> 6;
  const int l15 = lane & 15, l4 = lane >> 4;
  const int wr = wid >> 1, wc = wid & 1;
  const int fx = (((l4 << 4) ^ (((l15 >> 1) & 3) << 4)) >> 1);

  f32x4 acc[4][ACCN];
  #pragma unroll
  for (int i = 0; i < 4; ++i)
    #pragma unroll
    for (int j = 0; j < ACCN; ++j) acc[i][j] = (f32x4){0.f, 0.f, 0.f, 0.f};

  const __bf16* aptr = A + (size_t)row0 * lda;
  const __bf16* bptr = B + (size_t)col0 * ldb;

  auto stage = [&](int t, int p) {
    #pragma unroll
    for (int i = 0; i < 2; ++i) {
      int ch = tid + 256 * i;
      int rr = ch >> 2, kc = ch & 3;
      gload_lds16(aptr + (size_t)rr * lda + t * 32 + (kc ^ ((rr >> 1) & 3)) * 8,
                  &As[p * 4096 + ch * 8]);
    }
    #pragma unroll
    for (int i = 0; i < LB; ++i) {
      int ch = tid + 256 * i;
      int rr = ch >> 2, kc = ch & 3;
      gload_lds16(bptr + (size_t)rr * ldb + t * 32 + (kc ^ ((rr >> 1) & 3)) * 8,
                  &Bs[p * BN * 32 + ch * 8]);
    }
  };

  const int NT = K >> 5;
  stage(0, 0);
  stage(1, 1);
  int p = 0;
  for (int t = 0; t < NT; ++t) {
    bool stg = (t + 2 < NT);
    if (stg) {
      int ps = p + 2; if (ps >= 3) ps -= 3;
      stage(t + 2, ps);
    }
    waitvm(stg ? 2 * L : ((t + 1 < NT) ? L : 0));
    __builtin_amdgcn_sched_barrier(0);
    __builtin_amdgcn_s_barrier();
    __builtin_amdgcn_sched_barrier(0);
    bf16x8 af[4], bfr[ACCN];
    #pragma unroll
    for (int mi = 0; mi < 4; ++mi)
      af[mi] = *(const bf16x8*)&As[p * 4096 + (wr * 64 + mi * 16 + l15) * 32 + fx];
    #pragma unroll
    for (int ni = 0; ni < ACCN; ++ni)
      bfr[ni] = *(const bf16x8*)&Bs[p * BN * 32 + (wc * (BN / 2) + ni * 16 + l15) * 32 + fx];
    __builtin_amdgcn_s_setprio(1);
    #pragma unroll
    for (int mi = 0; mi < 4; ++mi)
      #pragma unroll
      for (int ni = 0; ni < ACCN; ++ni)
        acc[mi][ni] = MFMA16(af[mi], bfr[ni], acc[mi][ni]);
    __builtin_amdgcn_s_setprio(0);
    __builtin_amdgcn_sched_barrier(0);
    __builtin_amdgcn_s_barrier();
    __builtin_amdgcn_sched_barrier(0);
    p = (p == 2) ? 0 : p + 1;
  }

  #pragma unroll
  for (int mi = 0; mi < 4; ++mi)
    #pragma unroll
    for (int ni = 0; ni < ACCN; ++ni)
      #pragma unroll
      for (int rr = 0; rr < 4; ++rr) {
        int row = row0 + wr * 64 + mi * 16 + l4 * 4 + rr;
        int col = col0 + wc * (BN / 2) + ni * 16 + l15;
        float v = acc[mi][ni][rr];
        size_t off = (size_t)row * ldc + col;
        if (EPI == 0) {
          Cf[off] = v;
        } else if (EPI == 1) {
          Cb[off] = (__bf16)v;
        } else if (EPI == 2) {
          float gv = 0.5f * v * (1.0f + erff(v * 0.70710678118654752f));
          Cb[off] = (__bf16)gv;
        } else {
          Cf[off] = resid[off] + v;
        }
      }
}

// ---------------------------------------------------------------- sliding-window attention (r12 proven version)
__global__ __launch_bounds__(256) void attn_kernel(
    const __bf16* __restrict__ qkv, __bf16* __restrict__ o) {
  const int bid = blockIdx.x;
  const int qt = bid & 15, h = (bid >> 4) & 15, b = bid >> 8;
  const int qs = qt * 64;
  const int ntiles = (qt + 1 < 5) ? (qt + 1) : 5;
  const int kt0 = qt - (ntiles - 1);

  __shared__ __align__(16) __bf16 Qs[64][72];
  __shared__ __align__(16) __bf16 KVs[64][72];
  __shared__ __align__(16) __bf16 Ssm[64][328];
  __shared__ float rsum[64];

  const int tid = threadIdx.x;
  const int lane = tid & 63, wid = tid >> 6;
  const int l15 = lane & 15, l4 = lane >> 4;
  const size_t rs = 3072;
  const __bf16* qbase = qkv + ((size_t)(b * 1024 + qs)) * rs + h * 64;

  #pragma unroll
  for (int i = 0; i < 2; ++i) {
    int c = tid * 2 + i;
    int rr = c >> 3, dc = c & 7;
    *(u32x4*)&Qs[rr][dc * 8] = *(const u32x4*)(qbase + (size_t)rr * rs + dc * 8);
  }

  for (int it = 0; it < ntiles; ++it) {
    int kt = kt0 + it;
    const __bf16* kbase = qkv + ((size_t)(b * 1024 + kt * 64)) * rs + 1024 + h * 64;
    __syncthreads();
    #pragma unroll
    for (int i = 0; i < 2; ++i) {
      int c = tid * 2 + i;
      int rr = c >> 3, dc = c & 7;
      *(u32x4*)&KVs[rr][dc * 8] = *(const u32x4*)(kbase + (size_t)rr * rs + dc * 8);
    }
    __syncthreads();
    bf16x8 aq[2];
    #pragma unroll
    for (int kk = 0; kk < 2; ++kk)
      aq[kk] = *(const bf16x8*)&Qs[16 * wid + l15][kk * 32 + l4 * 8];
    #pragma unroll
    for (int n = 0; n < 4; ++n) {
      f32x4 c4 = (f32x4){0.f, 0.f, 0.f, 0.f};
      #pragma unroll
      for (int kk = 0; kk < 2; ++kk) {
        bf16x8 bk = *(const bf16x8*)&KVs[n * 16 + l15][kk * 32 + l4 * 8];
        c4 = MFMA16(aq[kk], bk, c4);
      }
      int kj = kt * 64 + n * 16 + l15;
      int colS = it * 64 + n * 16 + l15;
      #pragma unroll
      for (int rr = 0; rr < 4; ++rr) {
        int qi = qs + 16 * wid + l4 * 4 + rr;
        int d = qi - kj;
        float sv = c4[rr] * 0.125f;
        Ssm[16 * wid + l4 * 4 + rr][colS] =
            (d >= 0 && d < 256) ? (__bf16)sv : (__bf16)(-1e30f);
      }
    }
  }
  __syncthreads();

  const int nc = ntiles * 4;
  for (int ro = 0; ro < 4; ++ro) {
    int row = 16 * wid + ro * 4 + l4;
    float vals[20];
    #pragma unroll
    for (int i = 0; i < 20; ++i) vals[i] = -3e38f;
    #pragma unroll
    for (int i = 0; i < 20; ++i)
      if (i < nc) vals[i] = (float)Ssm[row][l15 + 16 * i];
    float m = vals[0];
    #pragma unroll
    for (int i = 1; i < 20; ++i) m = fmaxf(m, vals[i]);
    #pragma unroll
    for (int off = 8; off >= 1; off >>= 1) m = fmaxf(m, __shfl_xor(m, off));
    float s = 0.f;
    #pragma unroll
    for (int i = 0; i < 20; ++i)
      if (i < nc) {
        float pp = __expf(vals[i] - m);
        s += pp;
        Ssm[row][l15 + 16 * i] = (__bf16)pp;
      }
    #pragma unroll
    for (int off = 8; off >= 1; off >>= 1) s += __shfl_xor(s, off);
    if (l15 == 0) rsum[row] = s;
  }

  f32x4 oacc[4];
  #pragma unroll
  for (int n = 0; n < 4; ++n) oacc[n] = (f32x4){0.f, 0.f, 0.f, 0.f};

  for (int it = 0; it < ntiles; ++it) {
    int kt = kt0 + it;
    const __bf16* vbase = qkv + ((size_t)(b * 1024 + kt * 64)) * rs + 2048 + h * 64;
    __syncthreads();
    {
      int k0 = (tid >> 4) * 4, d0 = (tid & 15) * 4;
      bf16x4 vr[4];
      #pragma unroll
      for (int rr = 0; rr < 4; ++rr)
        vr[rr] = *(const bf16x4*)(vbase + (size_t)(k0 + rr) * rs + d0);
      #pragma unroll
      for (int j = 0; j < 4; ++j) {
        bf16x4 wv;
        #pragma unroll
        for (int rr = 0; rr < 4; ++rr) wv[rr] = vr[rr][j];
        *(bf16x4*)&KVs[d0 + j][k0] = wv;
      }
    }
    __syncthreads();
    #pragma unroll
    for (int kk = 0; kk < 2; ++kk) {
      bf16x8 ap = *(const bf16x8*)&Ssm[16 * wid + l15][it * 64 + kk * 32 + l4 * 8];
      #pragma unroll
      for (int n = 0; n < 4; ++n) {
        bf16x8 bv = *(const bf16x8*)&KVs[n * 16 + l15][kk * 32 + l4 * 8];
        oacc[n] = MFMA16(ap, bv, oacc[n]);
      }
    }
  }

  #pragma unroll
  for (int n = 0; n < 4; ++n)
    #pragma unroll
    for (int rr = 0; rr < 4; ++rr) {
      int qrow = 16 * wid + l4 * 4 + rr;
      float inv = 1.0f / rsum[qrow];
      size_t m = (size_t)(b * 1024 + qs + qrow);
      o[m * 1024 + h * 64 + n * 16 + l15] = (__bf16)(oacc[n][rr] * inv);
    }
}

// ---------------------------------------------------------------- launch
extern "C" void kernel_launch(void* const* d_in, const int* in_sizes, int n_in,
                              void* d_out, int out_size, void* d_ws, size_t ws_size,
                              hipStream_t stream) {
  (void)in_sizes; (void)n_in; (void)out_size;
  const int*   idx     = (const int*)d_in[0];
  const float* tok_emb = (const float*)d_in[1];
  const float* pos_emb = (const float*)d_in[2];
  const float* ln1_g   = (const float*)d_in[3];
  const float* ln1_b   = (const float*)d_in[4];
  const float* qkv_w   = (const float*)d_in[5];
  const float* out_w   = (const float*)d_in[6];
  const float* ln2_g   = (const float*)d_in[7];
  const float* ln2_b   = (const float*)d_in[8];
  const float* a_w1    = (const float*)d_in[9];
  const float* a_w2    = (const float*)d_in[10];
  const float* f_w1    = (const float*)d_in[11];
  const float* f_w2    = (const float*)d_in[12];
  const float* lnf_g   = (const float*)d_in[13];
  const float* lnf_b   = (const float*)d_in[14];
  const float* head_w  = (const float*)d_in[15];
  float* out = (float*)d_out;

  char* ws = (char*)d_ws;
  float*  x    = (float*)(ws);                    // 2048x1024 f32
  __bf16* h    = (__bf16*)(ws + 8388608);         // 2048x1024 bf16
  __bf16* qkv  = (__bf16*)(ws + 12582912);        // 2048x3072 bf16
  __bf16* oatt = (__bf16*)(ws + 25165824);        // 2048x1024 bf16
  __bf16* gcat = (__bf16*)(ws + 29360128);        // 2048x4096 bf16

  const bool full = ws_size >= 313000000ull;

  __bf16 *wq, *wo, *w1c, *w2c, *wh;
  if (full) {
    wq  = (__bf16*)(ws + 46137344);   // 8x3072x1024
    wo  = (__bf16*)(ws + 96468992);   // 8x1024x1024
    w1c = (__bf16*)(ws + 113246208);  // 8x4096x1024
    w2c = (__bf16*)(ws + 180355072);  // 8x1024x4096
    wh  = (__bf16*)(ws + 247463936);  // 32000x1024
    prepack_all<<<65152, 256, 0, stream>>>(
        qkv_w, out_w, a_w1, f_w1, a_w2, f_w2, head_w, wq, wo, w1c, w2c, wh);
  } else {
    wq  = (__bf16*)(ws + 46137344);
    wo  = (__bf16*)(ws + 52428800);
    w1c = (__bf16*)(ws + 54525952);
    w2c = (__bf16*)(ws + 62914560);
    wh  = (__bf16*)(ws + 46137344);
  }

  embed_kernel<<<2048, 256, 0, stream>>>(idx, tok_emb, pos_emb, x);

  for (int l = 0; l < 8; ++l) {
    const __bf16 *wq_l, *wo_l, *w1_l, *w2_l;
    if (full) {
      wq_l = wq + (size_t)l * 3072 * 1024;
      wo_l = wo + (size_t)l * 1024 * 1024;
      w1_l = w1c + (size_t)l * 4096 * 1024;
      w2_l = w2c + (size_t)l * 1024 * 4096;
    } else {
      cvt_kernel<<<1536, 256, 0, stream>>>(qkv_w + (size_t)l * 3072 * 1024, wq, 393216);
      cvt_kernel<<<512, 256, 0, stream>>>(out_w + (size_t)l * 1024 * 1024, wo, 131072);
      cat_w1_kernel<<<2048, 256, 0, stream>>>(
          a_w1 + (size_t)l * 2048 * 1024, f_w1 + (size_t)l * 2048 * 1024, w1c);
      cat_w2_kernel<<<2048, 256, 0, stream>>>(
          a_w2 + (size_t)l * 1024 * 2048, f_w2 + (size_t)l * 1024 * 2048, w2c);
      wq_l = wq; wo_l = wo; w1_l = w1c; w2_l = w2c;
    }

    ln_kernel<<<2048, 256, 0, stream>>>(x, ln1_g + l * 1024, ln1_b + l * 1024, h);
    gemm_bf16<128, 1><<<16 * 24, 256, 0, stream>>>(
        h, 1024, wq_l, 1024, 1024, nullptr, qkv, 3072, nullptr, 16);
    attn_kernel<<<512, 256, 0, stream>>>(qkv, oatt);
    gemm_bf16<64, 3><<<16 * 16, 256, 0, stream>>>(
        oatt, 1024, wo_l, 1024, 1024, x, nullptr, 1024, x, 16);
    ln_kernel<<<2048, 256, 0, stream>>>(x, ln2_g + l * 1024, ln2_b + l * 1024, h);
    gemm_bf16<128, 2><<<16 * 32, 256, 0, stream>>>(
        h, 1024, w1_l, 1024, 1024, nullptr, gcat, 4096, nullptr, 16);
    gemm_bf16<64, 3><<<16 * 16, 256, 0, stream>>>(
        gcat, 4096, w2_l, 4096, 4096, x, nullptr, 1024, x, 16);
  }

  if (!full) {
    cvt_kernel<<<16000, 256, 0, stream>>>(head_w, wh, 4096000);
  }
  ln_kernel<<<2048, 256, 0, stream>>>(x, lnf_g, lnf_b, h);
  gemm256<0><<<8 * 125, 512, 0, stream>>>(
      h, 1024, wh, 1024, 1024, out, nullptr, 32000, 8);
}